// Round 11
// baseline (368.137 us; speedup 1.0000x reference)
//
#include <hip/hip_runtime.h>
#include <cstdint>

#define DIN 512
#define DH  256
#define DOUT 64

typedef __attribute__((ext_vector_type(8))) short bf16x8;
typedef __attribute__((ext_vector_type(4))) float f32x4;
typedef unsigned int uint32;

__device__ __forceinline__ unsigned short f2bf(float f) {
    uint32 u = __float_as_uint(f);
    u += 0x7fff + ((u >> 16) & 1);          // RNE
    return (unsigned short)(u >> 16);
}
__device__ __forceinline__ float bflo(uint32 u) { return __uint_as_float(u << 16); }
__device__ __forceinline__ float bfhi(uint32 u) { return __uint_as_float(u & 0xffff0000u); }
__device__ __forceinline__ uint32 pk2(float lo, float hi) {
    return (uint32)f2bf(lo) | ((uint32)f2bf(hi) << 16);
}

// ---------------- edge_index dtype detection ----------------
__global__ void detect_i64(const unsigned long long* ei, int n_check,
                           unsigned long long bound, int* flag) {
    __shared__ int ok;
    if (threadIdx.x == 0) ok = 1;
    __syncthreads();
    int bad = 0;
    for (int i = threadIdx.x; i < n_check; i += blockDim.x) {
        if (ei[i] >= bound) bad = 1;
    }
    if (bad) ok = 0;
    __syncthreads();
    if (threadIdx.x == 0) *flag = ok;
}

__device__ __forceinline__ int get_idx(const void* ei, int is64, int pos) {
    if (is64) return (int)((const long long*)ei)[pos];
    return ((const int*)ei)[pos];
}

// ---------------- degree count / dinv ----------------
__global__ void count_deg(const void* ei, const int* flag, int E, int* counts) {
    const int is64 = *flag;
    int e = blockIdx.x * blockDim.x + threadIdx.x;
    if (e >= E) return;
    int d = get_idx(ei, is64, E + e);
    atomicAdd(&counts[d], 1);
}

__global__ void compute_dinv(const int* counts, float* dinv, int N) {
    int i = blockIdx.x * blockDim.x + threadIdx.x;
    if (i < N) dinv[i] = rsqrtf((float)counts[i] + 1.0f);
}

// ---------------- exclusive scan ----------------
#define SCAN_BLOCK 256
#define SCAN_ELEMS 1024

__global__ void scan1(const int* counts, int* out, int* blocksums, int N) {
    __shared__ int sh[SCAN_BLOCK];
    int base = blockIdx.x * SCAN_ELEMS;
    int t = threadIdx.x;
    int v[4];
    int s = 0;
    #pragma unroll
    for (int j = 0; j < 4; j++) {
        int idx = base + t * 4 + j;
        v[j] = (idx < N) ? counts[idx] : 0;
        s += v[j];
    }
    sh[t] = s;
    __syncthreads();
    for (int off = 1; off < SCAN_BLOCK; off <<= 1) {
        int x = (t >= off) ? sh[t - off] : 0;
        __syncthreads();
        sh[t] += x;
        __syncthreads();
    }
    int run = (t == 0) ? 0 : sh[t - 1];
    #pragma unroll
    for (int j = 0; j < 4; j++) {
        int idx = base + t * 4 + j;
        if (idx < N) out[idx] = run;
        run += v[j];
    }
    if (t == SCAN_BLOCK - 1) blocksums[blockIdx.x] = sh[t];
}

__global__ void scan2(int* blocksums, int NB) {
    __shared__ int sh[SCAN_BLOCK];
    int t = threadIdx.x;
    sh[t] = (t < NB) ? blocksums[t] : 0;
    __syncthreads();
    for (int off = 1; off < SCAN_BLOCK; off <<= 1) {
        int x = (t >= off) ? sh[t - off] : 0;
        __syncthreads();
        sh[t] += x;
        __syncthreads();
    }
    if (t < NB) blocksums[t] = (t == 0) ? 0 : sh[t - 1];
}

__global__ void scan3(int* row_ptr, const int* blocksums, int N, int E) {
    int i = blockIdx.x * blockDim.x + threadIdx.x;
    if (i < N) row_ptr[i] += blocksums[i / SCAN_ELEMS];
    if (i == N) row_ptr[N] = E;
}

// ---------------- CSR fill (packed edge: col + weight bits) ----------------
__global__ void fill_csr(const void* ei, const int* flag, int E,
                         const int* row_ptr, int* cursor, int2* edges,
                         const float* dinv) {
    const int is64 = *flag;
    int e = blockIdx.x * blockDim.x + threadIdx.x;
    if (e >= E) return;
    int d = get_idx(ei, is64, E + e);
    int s = get_idx(ei, is64, e);
    int pos = row_ptr[d] + atomicAdd(&cursor[d], 1);
    edges[pos] = make_int2(s, __float_as_int(dinv[s] * dinv[d]));
}

// ---------------- weight transpose+convert: W[K][Nw] f32 -> Bt[Nw][K] bf16 ----------------
__global__ void transpose_w(const float* __restrict__ W, unsigned short* __restrict__ Bt,
                            int K, int Nw) {
    int i = blockIdx.x * blockDim.x + threadIdx.x;
    if (i >= K * Nw) return;
    int k = i / Nw, n = i % Nw;
    Bt[(size_t)n * K + k] = f2bf(W[i]);
}

// ---------------- GEMM m97-style: C[M,256]=A[M,K]*Bt[256,K]^T, bf16 out ----------------
// BM=128 BN=128 BK=64, 256 threads (4 waves, 2x2). 32 KB LDS. 1-D grid:
// bid>>1 = m-tile, bid&1 = n-half -> both n-halves of an m-tile dispatch
// adjacently so the 2nd A pass hits L3. Proven XOR swizzle + 2-barrier loop.
template <bool A_FP32>
__global__ __launch_bounds__(256) void gemm_mfma(const void* __restrict__ Ap,
                                                 const unsigned short* __restrict__ Bt,
                                                 unsigned short* __restrict__ C,
                                                 int M, int K) {
    __shared__ unsigned short lds[16384];   // As[128][64] | Bs[128][64] = 32 KB
    unsigned short* As = lds;
    unsigned short* Bs = lds + 8192;
    const int tid = threadIdx.x;
    const int w = tid >> 6, l = tid & 63;
    const int m0 = (blockIdx.x >> 1) * 128;
    const int n0 = (blockIdx.x & 1) * 128;
    const int wr = w >> 1, wc = w & 1;      // 2x2 wave grid, each 64x64

    f32x4 acc[4][4] = {};

    for (int k0 = 0; k0 < K; k0 += 64) {
        // ---- stage B: 128x64 bf16 (1024 granules, 4/thread), src pre-swizzled ----
        #pragma unroll
        for (int i = 0; i < 4; i++) {
            int gi = i * 256 + tid;
            int row = gi >> 3, g = gi & 7;
            int gs = g ^ (row & 7);
            __builtin_amdgcn_global_load_lds(
                (const __attribute__((address_space(1))) uint32*)(Bt + (size_t)(n0 + row) * K + k0 + gs * 8),
                (__attribute__((address_space(3))) uint32*)(Bs + row * 64 + g * 8), 16, 0, 0);
        }
        // ---- stage A: 128x64 (1024 granules, 4/thread) ----
        if (A_FP32) {
            const float* Af = (const float*)Ap;
            #pragma unroll
            for (int i = 0; i < 4; i++) {
                int gi = i * 256 + tid;
                int row = gi >> 3, g = gi & 7;
                int rg = m0 + row; if (rg > M - 1) rg = M - 1;
                const float* s = Af + (size_t)rg * K + k0 + g * 8;
                float4 v0 = *(const float4*)s;
                float4 v1 = *(const float4*)(s + 4);
                uint4 o;
                o.x = pk2(v0.x, v0.y); o.y = pk2(v0.z, v0.w);
                o.z = pk2(v1.x, v1.y); o.w = pk2(v1.z, v1.w);
                *(uint4*)(As + row * 64 + ((g ^ (row & 7)) * 8)) = o;
            }
        } else {
            const unsigned short* Ab = (const unsigned short*)Ap;
            #pragma unroll
            for (int i = 0; i < 4; i++) {
                int gi = i * 256 + tid;
                int row = gi >> 3, g = gi & 7;
                int gs = g ^ (row & 7);
                int rg = m0 + row; if (rg > M - 1) rg = M - 1;
                __builtin_amdgcn_global_load_lds(
                    (const __attribute__((address_space(1))) uint32*)(Ab + (size_t)rg * K + k0 + gs * 8),
                    (__attribute__((address_space(3))) uint32*)(As + row * 64 + g * 8), 16, 0, 0);
            }
        }
        __syncthreads();
        // ---- compute (swizzled ds_read): 32 MFMA / wave / K-step ----
        #pragma unroll
        for (int ks = 0; ks < 2; ks++) {
            bf16x8 a[4], b[4];
            #pragma unroll
            for (int m = 0; m < 4; m++) {
                int ar = wr * 64 + m * 16 + (l & 15);
                int q = (ks * 4 + (l >> 4)) ^ (ar & 7);
                a[m] = *(const bf16x8*)(As + ar * 64 + q * 8);
            }
            #pragma unroll
            for (int n = 0; n < 4; n++) {
                int br = wc * 64 + n * 16 + (l & 15);
                int q = (ks * 4 + (l >> 4)) ^ (br & 7);
                b[n] = *(const bf16x8*)(Bs + br * 64 + q * 8);
            }
            #pragma unroll
            for (int m = 0; m < 4; m++)
                #pragma unroll
                for (int n = 0; n < 4; n++)
                    acc[m][n] = __builtin_amdgcn_mfma_f32_16x16x32_bf16(a[m], b[n], acc[m][n], 0, 0, 0);
        }
        __syncthreads();
    }

    // ---- epilogue: per-wave 64x64 region (8 KB x 4 = all 32 KB) ----
    unsigned short* ep = lds + w * 4096;
    #pragma unroll
    for (int m = 0; m < 4; m++)
        #pragma unroll
        for (int n = 0; n < 4; n++)
            #pragma unroll
            for (int r = 0; r < 4; r++)
                ep[(m * 16 + (l >> 4) * 4 + r) * 64 + n * 16 + (l & 15)] = f2bf(acc[m][n][r]);
    __syncthreads();
    #pragma unroll
    for (int p = 0; p < 8; p++) {
        int row = p * 8 + (l >> 3);
        int gr = m0 + wr * 64 + row;
        uint4 v = *(const uint4*)(ep + row * 64 + (l & 7) * 8);
        if (gr < M)
            *(uint4*)(C + (size_t)gr * 256 + n0 + wc * 64 + (l & 7) * 8) = v;
    }
}

// ---------------- GEMM2 persistent-B: C[M,256] = A[M,256] @ Bt[256,256]^T ----------------
// 512 threads (8 waves, 2x4). Whole Bt2 (128 KB) LDS-resident, loaded once.
__global__ __launch_bounds__(512) void gemm2_persist(const unsigned short* __restrict__ A,
                                                     const unsigned short* __restrict__ Bt,
                                                     unsigned short* __restrict__ C,
                                                     int M) {
    __shared__ unsigned short lds[73728];   // Bs 128 KB + As 2x8 KB = 144 KB
    unsigned short* Bs = lds;               // [256 rows(n)][256 cols(k)], swizzled granules
    unsigned short* As = lds + 65536;       // 2 bufs of 4096 ushorts ([64][64])
    const int tid = threadIdx.x;
    const int w = tid >> 6, l = tid & 63;
    const int wr = w >> 2, wc = w & 3;      // 2 x 4 wave grid

    // ---- load ALL of Bt once (8192 granules of 16B; 16 per thread) ----
    #pragma unroll
    for (int i = 0; i < 16; i++) {
        int gi = i * 512 + tid;             // 0..8191
        int r = gi >> 5, g = gi & 31;       // row, dest granule (32 granules/row)
        int gs = g ^ (r & 7);               // pre-swizzled source granule
        __builtin_amdgcn_global_load_lds(
            (const __attribute__((address_space(1))) uint32*)(Bt + (size_t)r * 256 + gs * 8),
            (__attribute__((address_space(3))) uint32*)(Bs + (size_t)gi * 8), 16, 0, 0);
    }

    const int sr = tid >> 3;                // A-stage row 0..63
    const int sg = tid & 7;                 // A-stage dest granule

    for (int mt = blockIdx.x; mt * 64 < M; mt += gridDim.x) {
        const int m0 = mt * 64;
        {
            int rg = m0 + sr; if (rg > M - 1) rg = M - 1;
            int gq = sg ^ (sr & 7);
            __builtin_amdgcn_global_load_lds(
                (const __attribute__((address_space(1))) uint32*)(A + (size_t)rg * 256 + gq * 8),
                (__attribute__((address_space(3))) uint32*)(As + tid * 8), 16, 0, 0);
        }
        __syncthreads();

        f32x4 acc[2][4] = {};
        #pragma unroll
        for (int k = 0; k < 4; k++) {
            if (k < 3) {
                int rg = m0 + sr; if (rg > M - 1) rg = M - 1;
                int gq = sg ^ (sr & 7);
                __builtin_amdgcn_global_load_lds(
                    (const __attribute__((address_space(1))) uint32*)(A + (size_t)rg * 256 + (k + 1) * 64 + gq * 8),
                    (__attribute__((address_space(3))) uint32*)(As + ((k + 1) & 1) * 4096 + tid * 8), 16, 0, 0);
            }
            const unsigned short* Ab = As + (k & 1) * 4096;
            #pragma unroll
            for (int ks = 0; ks < 2; ks++) {
                bf16x8 a[2], b[4];
                #pragma unroll
                for (int m = 0; m < 2; m++) {
                    int ar = wr * 32 + m * 16 + (l & 15);
                    int q = (ks * 4 + (l >> 4)) ^ (ar & 7);
                    a[m] = *(const bf16x8*)(Ab + ar * 64 + q * 8);
                }
                #pragma unroll
                for (int n = 0; n < 4; n++) {
                    int br = wc * 64 + n * 16 + (l & 15);
                    int gabs = k * 8 + ks * 4 + (l >> 4);
                    int q = gabs ^ (br & 7);
                    b[n] = *(const bf16x8*)(Bs + br * 256 + q * 8);
                }
                #pragma unroll
                for (int m = 0; m < 2; m++)
                    #pragma unroll
                    for (int n = 0; n < 4; n++)
                        acc[m][n] = __builtin_amdgcn_mfma_f32_16x16x32_bf16(a[m], b[n], acc[m][n], 0, 0, 0);
            }
            __syncthreads();
        }

        #pragma unroll
        for (int m = 0; m < 2; m++)
            #pragma unroll
            for (int r = 0; r < 4; r++) {
                int row = m0 + wr * 32 + m * 16 + (l >> 4) * 4 + r;
                if (row >= M) continue;
                #pragma unroll
                for (int n = 0; n < 4; n++) {
                    int col = wc * 64 + n * 16 + (l & 15);
                    C[(size_t)row * 256 + col] = f2bf(acc[m][n][r]);
                }
            }
    }
}

// ---------------- head GEMM: out[M,64] = A[M,256]*Bt[64,256]^T + bias, f32 out ----------------
__global__ __launch_bounds__(256) void gemm_head(const unsigned short* __restrict__ A,
                                                 const unsigned short* __restrict__ Bt,
                                                 const float* __restrict__ bias,
                                                 float* __restrict__ out, int M) {
    __shared__ unsigned short As[128 * 64];
    __shared__ unsigned short Bs[64 * 64];
    const int tid = threadIdx.x;
    const int w = tid >> 6, l = tid & 63;
    const int m0 = blockIdx.x * 128;
    const int wr = w >> 1, wc = w & 1;
    f32x4 acc[4][2] = {};

    for (int k0 = 0; k0 < 256; k0 += 64) {
        #pragma unroll
        for (int i = 0; i < 4; i++) {
            int row = i * 32 + (tid >> 3);
            int gq = (tid & 7) ^ (row & 7);
            int rg = m0 + row; if (rg > M - 1) rg = M - 1;
            __builtin_amdgcn_global_load_lds(
                (const __attribute__((address_space(1))) uint32*)(A + (size_t)rg * 256 + k0 + gq * 8),
                (__attribute__((address_space(3))) uint32*)(As + row * 64 + (tid & 7) * 8), 16, 0, 0);
        }
        #pragma unroll
        for (int i = 0; i < 2; i++) {
            int row = i * 32 + (tid >> 3);
            int gq = (tid & 7) ^ (row & 7);
            __builtin_amdgcn_global_load_lds(
                (const __attribute__((address_space(1))) uint32*)(Bt + (size_t)row * 256 + k0 + gq * 8),
                (__attribute__((address_space(3))) uint32*)(Bs + row * 64 + (tid & 7) * 8), 16, 0, 0);
        }
        __syncthreads();
        #pragma unroll
        for (int ks = 0; ks < 2; ks++) {
            bf16x8 a[4], b[2];
            #pragma unroll
            for (int m = 0; m < 4; m++) {
                int arow = wr * 64 + m * 16 + (l & 15);
                int ag = (ks * 4 + (l >> 4)) ^ (arow & 7);
                a[m] = *(const bf16x8*)(As + arow * 64 + ag * 8);
            }
            #pragma unroll
            for (int n = 0; n < 2; n++) {
                int brow = wc * 32 + n * 16 + (l & 15);
                int bg = (ks * 4 + (l >> 4)) ^ (brow & 7);
                b[n] = *(const bf16x8*)(Bs + brow * 64 + bg * 8);
            }
            #pragma unroll
            for (int m = 0; m < 4; m++)
                #pragma unroll
                for (int n = 0; n < 2; n++)
                    acc[m][n] = __builtin_amdgcn_mfma_f32_16x16x32_bf16(a[m], b[n], acc[m][n], 0, 0, 0);
        }
        __syncthreads();
    }
    #pragma unroll
    for (int m = 0; m < 4; m++)
        #pragma unroll
        for (int n = 0; n < 2; n++)
            #pragma unroll
            for (int r = 0; r < 4; r++) {
                int gr = m0 + wr * 64 + m * 16 + (l >> 4) * 4 + r;
                int col = wc * 32 + n * 16 + (l & 15);
                if (gr < M) out[(size_t)gr * 64 + col] = acc[m][n][r] + bias[col];
            }
}

// ---------------- aggregation: 2 nodes/wave, 16B lanes, packed edges, 4x unroll ----------------
#define ACC8(v, wgt)                                    \
    do {                                                \
        acc[0] = fmaf(wgt, bflo(v.x), acc[0]);          \
        acc[1] = fmaf(wgt, bfhi(v.x), acc[1]);          \
        acc[2] = fmaf(wgt, bflo(v.y), acc[2]);          \
        acc[3] = fmaf(wgt, bfhi(v.y), acc[3]);          \
        acc[4] = fmaf(wgt, bflo(v.z), acc[4]);          \
        acc[5] = fmaf(wgt, bfhi(v.z), acc[5]);          \
        acc[6] = fmaf(wgt, bflo(v.w), acc[6]);          \
        acc[7] = fmaf(wgt, bfhi(v.w), acc[7]);          \
    } while (0)

__global__ __launch_bounds__(256) void aggregate_bf(const unsigned short* __restrict__ t,
                                                    const float* __restrict__ dinv,
                                                    const int* __restrict__ row_ptr,
                                                    const int2* __restrict__ edges,
                                                    const float* __restrict__ bias,
                                                    unsigned short* __restrict__ outb,
                                                    int N) {
    int wave = threadIdx.x >> 6;
    int lane = threadIdx.x & 63;
    int half = lane >> 5;          // which node of the pair
    int sl = lane & 31;            // owns feats [sl*8, sl*8+8)
    int n = blockIdx.x * 8 + wave * 2 + half;
    if (n >= N) return;

    float dn = dinv[n];
    int r0 = row_ptr[n], r1 = row_ptr[n + 1];

    float acc[8];
    {
        uint4 sv = *(const uint4*)(t + (size_t)n * DH + sl * 8);
        float sn = dn * dn;
        acc[0] = bflo(sv.x) * sn; acc[1] = bfhi(sv.x) * sn;
        acc[2] = bflo(sv.y) * sn; acc[3] = bfhi(sv.y) * sn;
        acc[4] = bflo(sv.z) * sn; acc[5] = bfhi(sv.z) * sn;
        acc[6] = bflo(sv.w) * sn; acc[7] = bfhi(sv.w) * sn;
    }

    int j = r0;
    for (; j + 4 <= r1; j += 4) {
        int2 e0 = edges[j + 0], e1 = edges[j + 1];
        int2 e2 = edges[j + 2], e3 = edges[j + 3];
        uint4 v0 = *(const uint4*)(t + (size_t)e0.x * DH + sl * 8);
        uint4 v1 = *(const uint4*)(t + (size_t)e1.x * DH + sl * 8);
        uint4 v2 = *(const uint4*)(t + (size_t)e2.x * DH + sl * 8);
        uint4 v3 = *(const uint4*)(t + (size_t)e3.x * DH + sl * 8);
        float w0 = __int_as_float(e0.y), w1 = __int_as_float(e1.y);
        float w2 = __int_as_float(e2.y), w3 = __int_as_float(e3.y);
        ACC8(v0, w0); ACC8(v1, w1); ACC8(v2, w2); ACC8(v3, w3);
    }
    for (; j < r1; j++) {
        int2 e = edges[j];
        float wgt = __int_as_float(e.y);
        uint4 v = *(const uint4*)(t + (size_t)e.x * DH + sl * 8);
        ACC8(v, wgt);
    }

    float4 b0 = *(const float4*)(bias + sl * 8);
    float4 b1v = *(const float4*)(bias + sl * 8 + 4);
    acc[0] = fmaxf(acc[0] + b0.x, 0.f);  acc[1] = fmaxf(acc[1] + b0.y, 0.f);
    acc[2] = fmaxf(acc[2] + b0.z, 0.f);  acc[3] = fmaxf(acc[3] + b0.w, 0.f);
    acc[4] = fmaxf(acc[4] + b1v.x, 0.f); acc[5] = fmaxf(acc[5] + b1v.y, 0.f);
    acc[6] = fmaxf(acc[6] + b1v.z, 0.f); acc[7] = fmaxf(acc[7] + b1v.w, 0.f);

    uint4 o;
    o.x = pk2(acc[0], acc[1]);
    o.y = pk2(acc[2], acc[3]);
    o.z = pk2(acc[4], acc[5]);
    o.w = pk2(acc[6], acc[7]);
    *(uint4*)(outb + (size_t)n * DH + sl * 8) = o;
}

// ---------------- launch ----------------
extern "C" void kernel_launch(void* const* d_in, const int* in_sizes, int n_in,
                              void* d_out, int out_size, void* d_ws, size_t ws_size,
                              hipStream_t stream) {
    const float* x  = (const float*)d_in[0];
    const void*  ei = d_in[1];
    const float* W1 = (const float*)d_in[2];
    const float* b1 = (const float*)d_in[3];
    const float* W2 = (const float*)d_in[4];
    const float* b2 = (const float*)d_in[5];
    const float* Wc = (const float*)d_in[6];
    const float* bc = (const float*)d_in[7];
    float* out = (float*)d_out;

    const int N = in_sizes[0] / DIN;   // 100000
    const int E = in_sizes[1] / 2;     // 800000

    char* ws = (char*)d_ws;
    size_t off = 0;
    auto alloc = [&](size_t bytes) -> void* {
        off = (off + 255) & ~(size_t)255;
        void* p = ws + off;
        off += bytes;
        return p;
    };

    int*   flag      = (int*)alloc(4);
    int*   counts    = (int*)alloc((size_t)N * 4);   // counts + cursor contiguous:
    int*   cursor    = (int*)alloc((size_t)N * 4);   // one memset clears both
    int*   row_ptr   = (int*)alloc((size_t)(N + 1) * 4);
    int2*  edges     = (int2*)alloc((size_t)E * 8);
    int*   blocksums = (int*)alloc(1024 * 4);
    float* dinv      = (float*)alloc((size_t)N * 4);
    unsigned short* Bt1   = (unsigned short*)alloc((size_t)DH * DIN * 2);
    unsigned short* Bt2   = (unsigned short*)alloc((size_t)DH * DH * 2);
    unsigned short* Btc   = (unsigned short*)alloc((size_t)DOUT * DH * 2);
    unsigned short* t_buf = (unsigned short*)alloc((size_t)N * DH * 2);
    unsigned short* a_buf = (unsigned short*)alloc((size_t)N * DH * 2);

    const int NB = (N + SCAN_ELEMS - 1) / SCAN_ELEMS;
    const int gM128 = (N + 127) / 128;

    // dtype detection + weight prep
    detect_i64<<<1, 256, 0, stream>>>((const unsigned long long*)ei, 1024,
                                      (unsigned long long)N, flag);
    transpose_w<<<(DIN * DH + 255) / 256, 256, 0, stream>>>(W1, Bt1, DIN, DH);
    transpose_w<<<(DH * DH + 255) / 256, 256, 0, stream>>>(W2, Bt2, DH, DH);
    transpose_w<<<(DH * DOUT + 255) / 256, 256, 0, stream>>>(Wc, Btc, DH, DOUT);

    // degrees + CSR (single memset clears counts AND cursor)
    hipMemsetAsync(counts, 0, (size_t)N * 8 + 256, stream);
    count_deg<<<(E + 255) / 256, 256, 0, stream>>>(ei, flag, E, counts);
    compute_dinv<<<(N + 255) / 256, 256, 0, stream>>>(counts, dinv, N);
    scan1<<<NB, SCAN_BLOCK, 0, stream>>>(counts, row_ptr, blocksums, N);
    scan2<<<1, SCAN_BLOCK, 0, stream>>>(blocksums, NB);
    scan3<<<(N + 1 + 255) / 256, 256, 0, stream>>>(row_ptr, blocksums, N, E);
    fill_csr<<<(E + 255) / 256, 256, 0, stream>>>(ei, flag, E, row_ptr, cursor, edges, dinv);

    // layer 1 (m97 128x128 tile, n-half adjacent dispatch)
    gemm_mfma<true><<<2 * gM128, 256, 0, stream>>>(x, Bt1, t_buf, N, DIN);
    aggregate_bf<<<(N + 7) / 8, 256, 0, stream>>>(t_buf, dinv, row_ptr, edges, b1, a_buf, N);
    // layer 2 (persistent-B)
    gemm2_persist<<<256, 512, 0, stream>>>(a_buf, Bt2, t_buf, N);
    aggregate_bf<<<(N + 7) / 8, 256, 0, stream>>>(t_buf, dinv, row_ptr, edges, b2, a_buf, N);
    // head
    gemm_head<<<gM128, 256, 0, stream>>>(a_buf, Btc, bc, out, N);
}

// Round 12
// 353.896 us; speedup vs baseline: 1.0402x; 1.0402x over previous
//
#include <hip/hip_runtime.h>
#include <cstdint>

#define DIN 512
#define DH  256
#define DOUT 64

typedef __attribute__((ext_vector_type(8))) short bf16x8;
typedef __attribute__((ext_vector_type(4))) float f32x4;
typedef unsigned int uint32;

__device__ __forceinline__ unsigned short f2bf(float f) {
    uint32 u = __float_as_uint(f);
    u += 0x7fff + ((u >> 16) & 1);          // RNE
    return (unsigned short)(u >> 16);
}
__device__ __forceinline__ float bflo(uint32 u) { return __uint_as_float(u << 16); }
__device__ __forceinline__ float bfhi(uint32 u) { return __uint_as_float(u & 0xffff0000u); }
__device__ __forceinline__ uint32 pk2(float lo, float hi) {
    return (uint32)f2bf(lo) | ((uint32)f2bf(hi) << 16);
}

// ---------------- edge_index dtype detection ----------------
__global__ void detect_i64(const unsigned long long* ei, int n_check,
                           unsigned long long bound, int* flag) {
    __shared__ int ok;
    if (threadIdx.x == 0) ok = 1;
    __syncthreads();
    int bad = 0;
    for (int i = threadIdx.x; i < n_check; i += blockDim.x) {
        if (ei[i] >= bound) bad = 1;
    }
    if (bad) ok = 0;
    __syncthreads();
    if (threadIdx.x == 0) *flag = ok;
}

__device__ __forceinline__ int get_idx(const void* ei, int is64, int pos) {
    if (is64) return (int)((const long long*)ei)[pos];
    return ((const int*)ei)[pos];
}

// ---------------- degree count / dinv ----------------
__global__ void count_deg(const void* ei, const int* flag, int E, int* counts) {
    const int is64 = *flag;
    int e = blockIdx.x * blockDim.x + threadIdx.x;
    if (e >= E) return;
    int d = get_idx(ei, is64, E + e);
    atomicAdd(&counts[d], 1);
}

__global__ void compute_dinv(const int* counts, float* dinv, int N) {
    int i = blockIdx.x * blockDim.x + threadIdx.x;
    if (i < N) dinv[i] = rsqrtf((float)counts[i] + 1.0f);
}

// ---------------- exclusive scan ----------------
#define SCAN_BLOCK 256
#define SCAN_ELEMS 1024

__global__ void scan1(const int* counts, int* out, int* blocksums, int N) {
    __shared__ int sh[SCAN_BLOCK];
    int base = blockIdx.x * SCAN_ELEMS;
    int t = threadIdx.x;
    int v[4];
    int s = 0;
    #pragma unroll
    for (int j = 0; j < 4; j++) {
        int idx = base + t * 4 + j;
        v[j] = (idx < N) ? counts[idx] : 0;
        s += v[j];
    }
    sh[t] = s;
    __syncthreads();
    for (int off = 1; off < SCAN_BLOCK; off <<= 1) {
        int x = (t >= off) ? sh[t - off] : 0;
        __syncthreads();
        sh[t] += x;
        __syncthreads();
    }
    int run = (t == 0) ? 0 : sh[t - 1];
    #pragma unroll
    for (int j = 0; j < 4; j++) {
        int idx = base + t * 4 + j;
        if (idx < N) out[idx] = run;
        run += v[j];
    }
    if (t == SCAN_BLOCK - 1) blocksums[blockIdx.x] = sh[t];
}

__global__ void scan2(int* blocksums, int NB) {
    __shared__ int sh[SCAN_BLOCK];
    int t = threadIdx.x;
    sh[t] = (t < NB) ? blocksums[t] : 0;
    __syncthreads();
    for (int off = 1; off < SCAN_BLOCK; off <<= 1) {
        int x = (t >= off) ? sh[t - off] : 0;
        __syncthreads();
        sh[t] += x;
        __syncthreads();
    }
    if (t < NB) blocksums[t] = (t == 0) ? 0 : sh[t - 1];
}

__global__ void scan3(int* row_ptr, const int* blocksums, int N, int E) {
    int i = blockIdx.x * blockDim.x + threadIdx.x;
    if (i < N) row_ptr[i] += blocksums[i / SCAN_ELEMS];
    if (i == N) row_ptr[N] = E;
}

// ---------------- CSR fill (packed edge: col + weight bits) ----------------
__global__ void fill_csr(const void* ei, const int* flag, int E,
                         const int* row_ptr, int* cursor, int2* edges,
                         const float* dinv) {
    const int is64 = *flag;
    int e = blockIdx.x * blockDim.x + threadIdx.x;
    if (e >= E) return;
    int d = get_idx(ei, is64, E + e);
    int s = get_idx(ei, is64, e);
    int pos = row_ptr[d] + atomicAdd(&cursor[d], 1);
    edges[pos] = make_int2(s, __float_as_int(dinv[s] * dinv[d]));
}

// ---------------- weight transpose+convert: W[K][Nw] f32 -> Bt[Nw][K] bf16 ----------------
__global__ void transpose_w(const float* __restrict__ W, unsigned short* __restrict__ Bt,
                            int K, int Nw) {
    int i = blockIdx.x * blockDim.x + threadIdx.x;
    if (i >= K * Nw) return;
    int k = i / Nw, n = i % Nw;
    Bt[(size_t)n * K + k] = f2bf(W[i]);
}

// ---------------- GEMM1 (round-4/10 proven): C[M,256]=A[M,K]*Bt[256,K]^T ----------------
// BM=64 BN=256 BK=64, 256 threads (4 waves). A+B staged, XOR-swizzled LDS, 40 KB.
template <bool A_FP32>
__global__ __launch_bounds__(256) void gemm_mfma(const void* __restrict__ Ap,
                                                 const unsigned short* __restrict__ Bt,
                                                 unsigned short* __restrict__ C,
                                                 int M, int K) {
    __shared__ unsigned short lds[20480];   // As[64][64] | Bs[256][64] = 40 KB
    unsigned short* As = lds;
    unsigned short* Bs = lds + 4096;
    const int tid = threadIdx.x;
    const int w = tid >> 6, l = tid & 63;
    const int m0 = blockIdx.x * 64;

    f32x4 acc[4][4] = {};

    for (int k0 = 0; k0 < K; k0 += 64) {
        // ---- stage B: 256x64 bf16, source granule pre-swizzled ----
        #pragma unroll
        for (int i = 0; i < 8; i++) {
            int row = i * 32 + (tid >> 3);
            int gq = (tid & 7) ^ (row & 7);
            const unsigned short* src = Bt + (size_t)row * K + k0 + gq * 8;
            unsigned short* dst = Bs + row * 64 + (tid & 7) * 8;
            __builtin_amdgcn_global_load_lds(
                (const __attribute__((address_space(1))) uint32*)src,
                (__attribute__((address_space(3))) uint32*)dst, 16, 0, 0);
        }
        // ---- stage A: 64x64 ----
        if (A_FP32) {
            const float* Af = (const float*)Ap;
            #pragma unroll
            for (int i = 0; i < 2; i++) {
                int row = i * 32 + (tid >> 3);
                int g = tid & 7;
                int rg = m0 + row; if (rg > M - 1) rg = M - 1;
                const float* s = Af + (size_t)rg * K + k0 + g * 8;
                float4 v0 = *(const float4*)s;
                float4 v1 = *(const float4*)(s + 4);
                uint4 o;
                o.x = pk2(v0.x, v0.y); o.y = pk2(v0.z, v0.w);
                o.z = pk2(v1.x, v1.y); o.w = pk2(v1.z, v1.w);
                *(uint4*)(As + row * 64 + ((g ^ (row & 7)) * 8)) = o;
            }
        } else {
            const unsigned short* Ab = (const unsigned short*)Ap;
            #pragma unroll
            for (int i = 0; i < 2; i++) {
                int row = i * 32 + (tid >> 3);
                int gq = (tid & 7) ^ (row & 7);
                int rg = m0 + row; if (rg > M - 1) rg = M - 1;
                const unsigned short* src = Ab + (size_t)rg * K + k0 + gq * 8;
                unsigned short* dst = As + row * 64 + (tid & 7) * 8;
                __builtin_amdgcn_global_load_lds(
                    (const __attribute__((address_space(1))) uint32*)src,
                    (__attribute__((address_space(3))) uint32*)dst, 16, 0, 0);
            }
        }
        __syncthreads();
        // ---- compute (swizzled ds_read) ----
        #pragma unroll
        for (int ks = 0; ks < 2; ks++) {
            bf16x8 a[4], b[4];
            #pragma unroll
            for (int m = 0; m < 4; m++) {
                int arow = m * 16 + (l & 15);
                int ag = (ks * 4 + (l >> 4)) ^ (arow & 7);
                a[m] = *(const bf16x8*)(As + arow * 64 + ag * 8);
            }
            #pragma unroll
            for (int n = 0; n < 4; n++) {
                int brow = w * 64 + n * 16 + (l & 15);
                int bg = (ks * 4 + (l >> 4)) ^ (brow & 7);
                b[n] = *(const bf16x8*)(Bs + brow * 64 + bg * 8);
            }
            #pragma unroll
            for (int m = 0; m < 4; m++)
                #pragma unroll
                for (int n = 0; n < 4; n++)
                    acc[m][n] = __builtin_amdgcn_mfma_f32_16x16x32_bf16(a[m], b[n], acc[m][n], 0, 0, 0);
        }
        __syncthreads();
    }

    // ---- epilogue: per-wave 64x64 region -> coalesced 16B stores ----
    unsigned short* ep = lds + w * 4096;
    #pragma unroll
    for (int m = 0; m < 4; m++)
        #pragma unroll
        for (int n = 0; n < 4; n++)
            #pragma unroll
            for (int r = 0; r < 4; r++)
                ep[(m * 16 + (l >> 4) * 4 + r) * 64 + n * 16 + (l & 15)] = f2bf(acc[m][n][r]);
    __syncthreads();
    #pragma unroll
    for (int p = 0; p < 8; p++) {
        int row = p * 8 + (l >> 3);
        int gr = m0 + row;
        uint4 v = *(const uint4*)(ep + row * 64 + (l & 7) * 8);
        if (gr < M)
            *(uint4*)(C + (size_t)gr * 256 + w * 64 + (l & 7) * 8) = v;
    }
}

// ---------------- GEMM2 persistent-B: C[M,256] = A[M,256] @ Bt[256,256]^T ----------------
// 512 threads (8 waves, 2x4). Whole Bt2 (128 KB) LDS-resident, loaded once.
__global__ __launch_bounds__(512) void gemm2_persist(const unsigned short* __restrict__ A,
                                                     const unsigned short* __restrict__ Bt,
                                                     unsigned short* __restrict__ C,
                                                     int M) {
    __shared__ unsigned short lds[73728];   // Bs 128 KB + As 2x8 KB = 144 KB
    unsigned short* Bs = lds;               // [256 rows(n)][256 cols(k)], swizzled granules
    unsigned short* As = lds + 65536;       // 2 bufs of 4096 ushorts ([64][64])
    const int tid = threadIdx.x;
    const int w = tid >> 6, l = tid & 63;
    const int wr = w >> 2, wc = w & 3;      // 2 x 4 wave grid

    // ---- load ALL of Bt once (8192 granules of 16B; 16 per thread) ----
    #pragma unroll
    for (int i = 0; i < 16; i++) {
        int gi = i * 512 + tid;             // 0..8191
        int r = gi >> 5, g = gi & 31;       // row, dest granule (32 granules/row)
        int gs = g ^ (r & 7);               // pre-swizzled source granule
        __builtin_amdgcn_global_load_lds(
            (const __attribute__((address_space(1))) uint32*)(Bt + (size_t)r * 256 + gs * 8),
            (__attribute__((address_space(3))) uint32*)(Bs + (size_t)gi * 8), 16, 0, 0);
    }

    const int sr = tid >> 3;                // A-stage row 0..63
    const int sg = tid & 7;                 // A-stage dest granule

    for (int mt = blockIdx.x; mt * 64 < M; mt += gridDim.x) {
        const int m0 = mt * 64;
        {
            int rg = m0 + sr; if (rg > M - 1) rg = M - 1;
            int gq = sg ^ (sr & 7);
            __builtin_amdgcn_global_load_lds(
                (const __attribute__((address_space(1))) uint32*)(A + (size_t)rg * 256 + gq * 8),
                (__attribute__((address_space(3))) uint32*)(As + tid * 8), 16, 0, 0);
        }
        __syncthreads();

        f32x4 acc[2][4] = {};
        #pragma unroll
        for (int k = 0; k < 4; k++) {
            if (k < 3) {
                int rg = m0 + sr; if (rg > M - 1) rg = M - 1;
                int gq = sg ^ (sr & 7);
                __builtin_amdgcn_global_load_lds(
                    (const __attribute__((address_space(1))) uint32*)(A + (size_t)rg * 256 + (k + 1) * 64 + gq * 8),
                    (__attribute__((address_space(3))) uint32*)(As + ((k + 1) & 1) * 4096 + tid * 8), 16, 0, 0);
            }
            const unsigned short* Ab = As + (k & 1) * 4096;
            #pragma unroll
            for (int ks = 0; ks < 2; ks++) {
                bf16x8 a[2], b[4];
                #pragma unroll
                for (int m = 0; m < 2; m++) {
                    int ar = wr * 32 + m * 16 + (l & 15);
                    int q = (ks * 4 + (l >> 4)) ^ (ar & 7);
                    a[m] = *(const bf16x8*)(Ab + ar * 64 + q * 8);
                }
                #pragma unroll
                for (int n = 0; n < 4; n++) {
                    int br = wc * 64 + n * 16 + (l & 15);
                    int gabs = k * 8 + ks * 4 + (l >> 4);
                    int q = gabs ^ (br & 7);
                    b[n] = *(const bf16x8*)(Bs + br * 256 + q * 8);
                }
                #pragma unroll
                for (int m = 0; m < 2; m++)
                    #pragma unroll
                    for (int n = 0; n < 4; n++)
                        acc[m][n] = __builtin_amdgcn_mfma_f32_16x16x32_bf16(a[m], b[n], acc[m][n], 0, 0, 0);
            }
            __syncthreads();
        }

        #pragma unroll
        for (int m = 0; m < 2; m++)
            #pragma unroll
            for (int r = 0; r < 4; r++) {
                int row = m0 + wr * 32 + m * 16 + (l >> 4) * 4 + r;
                if (row >= M) continue;
                #pragma unroll
                for (int n = 0; n < 4; n++) {
                    int col = wc * 64 + n * 16 + (l & 15);
                    C[(size_t)row * 256 + col] = f2bf(acc[m][n][r]);
                }
            }
    }
}

// ---------------- head GEMM: out[M,64] = A[M,256]*Bt[64,256]^T + bias, f32 out ----------------
__global__ __launch_bounds__(256) void gemm_head(const unsigned short* __restrict__ A,
                                                 const unsigned short* __restrict__ Bt,
                                                 const float* __restrict__ bias,
                                                 float* __restrict__ out, int M) {
    __shared__ unsigned short As[128 * 64];
    __shared__ unsigned short Bs[64 * 64];
    const int tid = threadIdx.x;
    const int w = tid >> 6, l = tid & 63;
    const int m0 = blockIdx.x * 128;
    const int wr = w >> 1, wc = w & 1;
    f32x4 acc[4][2] = {};

    for (int k0 = 0; k0 < 256; k0 += 64) {
        #pragma unroll
        for (int i = 0; i < 4; i++) {
            int row = i * 32 + (tid >> 3);
            int gq = (tid & 7) ^ (row & 7);
            int rg = m0 + row; if (rg > M - 1) rg = M - 1;
            __builtin_amdgcn_global_load_lds(
                (const __attribute__((address_space(1))) uint32*)(A + (size_t)rg * 256 + k0 + gq * 8),
                (__attribute__((address_space(3))) uint32*)(As + row * 64 + (tid & 7) * 8), 16, 0, 0);
        }
        #pragma unroll
        for (int i = 0; i < 2; i++) {
            int row = i * 32 + (tid >> 3);
            int gq = (tid & 7) ^ (row & 7);
            __builtin_amdgcn_global_load_lds(
                (const __attribute__((address_space(1))) uint32*)(Bt + (size_t)row * 256 + k0 + gq * 8),
                (__attribute__((address_space(3))) uint32*)(Bs + row * 64 + (tid & 7) * 8), 16, 0, 0);
        }
        __syncthreads();
        #pragma unroll
        for (int ks = 0; ks < 2; ks++) {
            bf16x8 a[4], b[2];
            #pragma unroll
            for (int m = 0; m < 4; m++) {
                int arow = wr * 64 + m * 16 + (l & 15);
                int ag = (ks * 4 + (l >> 4)) ^ (arow & 7);
                a[m] = *(const bf16x8*)(As + arow * 64 + ag * 8);
            }
            #pragma unroll
            for (int n = 0; n < 2; n++) {
                int brow = wc * 32 + n * 16 + (l & 15);
                int bg = (ks * 4 + (l >> 4)) ^ (brow & 7);
                b[n] = *(const bf16x8*)(Bs + brow * 64 + bg * 8);
            }
            #pragma unroll
            for (int m = 0; m < 4; m++)
                #pragma unroll
                for (int n = 0; n < 2; n++)
                    acc[m][n] = __builtin_amdgcn_mfma_f32_16x16x32_bf16(a[m], b[n], acc[m][n], 0, 0, 0);
        }
        __syncthreads();
    }
    #pragma unroll
    for (int m = 0; m < 4; m++)
        #pragma unroll
        for (int n = 0; n < 2; n++)
            #pragma unroll
            for (int r = 0; r < 4; r++) {
                int gr = m0 + wr * 64 + m * 16 + (l >> 4) * 4 + r;
                int col = wc * 32 + n * 16 + (l & 15);
                if (gr < M) out[(size_t)gr * 64 + col] = acc[m][n][r] + bias[col];
            }
}

// ---------------- aggregation: 2 nodes/wave, 16B lanes, packed edges, 8x unroll ----------------
#define ACC8(v, wgt)                                    \
    do {                                                \
        acc[0] = fmaf(wgt, bflo(v.x), acc[0]);          \
        acc[1] = fmaf(wgt, bfhi(v.x), acc[1]);          \
        acc[2] = fmaf(wgt, bflo(v.y), acc[2]);          \
        acc[3] = fmaf(wgt, bfhi(v.y), acc[3]);          \
        acc[4] = fmaf(wgt, bflo(v.z), acc[4]);          \
        acc[5] = fmaf(wgt, bfhi(v.z), acc[5]);          \
        acc[6] = fmaf(wgt, bflo(v.w), acc[6]);          \
        acc[7] = fmaf(wgt, bfhi(v.w), acc[7]);          \
    } while (0)

__global__ __launch_bounds__(256) void aggregate_bf(const unsigned short* __restrict__ t,
                                                    const float* __restrict__ dinv,
                                                    const int* __restrict__ row_ptr,
                                                    const int2* __restrict__ edges,
                                                    const float* __restrict__ bias,
                                                    unsigned short* __restrict__ outb,
                                                    int N) {
    int wave = threadIdx.x >> 6;
    int lane = threadIdx.x & 63;
    int half = lane >> 5;          // which node of the pair
    int sl = lane & 31;            // owns feats [sl*8, sl*8+8)
    int n = blockIdx.x * 8 + wave * 2 + half;
    if (n >= N) return;

    float dn = dinv[n];
    int r0 = row_ptr[n], r1 = row_ptr[n + 1];

    float acc[8];
    {
        uint4 sv = *(const uint4*)(t + (size_t)n * DH + sl * 8);
        float sn = dn * dn;
        acc[0] = bflo(sv.x) * sn; acc[1] = bfhi(sv.x) * sn;
        acc[2] = bflo(sv.y) * sn; acc[3] = bfhi(sv.y) * sn;
        acc[4] = bflo(sv.z) * sn; acc[5] = bfhi(sv.z) * sn;
        acc[6] = bflo(sv.w) * sn; acc[7] = bfhi(sv.w) * sn;
    }

    int j = r0;
    // 8-deep batch: 8 independent 512B row gathers in flight (mean degree = 8)
    for (; j + 8 <= r1; j += 8) {
        int2 e0 = edges[j + 0], e1 = edges[j + 1];
        int2 e2 = edges[j + 2], e3 = edges[j + 3];
        int2 e4 = edges[j + 4], e5 = edges[j + 5];
        int2 e6 = edges[j + 6], e7 = edges[j + 7];
        uint4 v0 = *(const uint4*)(t + (size_t)e0.x * DH + sl * 8);
        uint4 v1 = *(const uint4*)(t + (size_t)e1.x * DH + sl * 8);
        uint4 v2 = *(const uint4*)(t + (size_t)e2.x * DH + sl * 8);
        uint4 v3 = *(const uint4*)(t + (size_t)e3.x * DH + sl * 8);
        uint4 v4 = *(const uint4*)(t + (size_t)e4.x * DH + sl * 8);
        uint4 v5 = *(const uint4*)(t + (size_t)e5.x * DH + sl * 8);
        uint4 v6 = *(const uint4*)(t + (size_t)e6.x * DH + sl * 8);
        uint4 v7 = *(const uint4*)(t + (size_t)e7.x * DH + sl * 8);
        ACC8(v0, __int_as_float(e0.y)); ACC8(v1, __int_as_float(e1.y));
        ACC8(v2, __int_as_float(e2.y)); ACC8(v3, __int_as_float(e3.y));
        ACC8(v4, __int_as_float(e4.y)); ACC8(v5, __int_as_float(e5.y));
        ACC8(v6, __int_as_float(e6.y)); ACC8(v7, __int_as_float(e7.y));
    }
    for (; j + 4 <= r1; j += 4) {
        int2 e0 = edges[j + 0], e1 = edges[j + 1];
        int2 e2 = edges[j + 2], e3 = edges[j + 3];
        uint4 v0 = *(const uint4*)(t + (size_t)e0.x * DH + sl * 8);
        uint4 v1 = *(const uint4*)(t + (size_t)e1.x * DH + sl * 8);
        uint4 v2 = *(const uint4*)(t + (size_t)e2.x * DH + sl * 8);
        uint4 v3 = *(const uint4*)(t + (size_t)e3.x * DH + sl * 8);
        ACC8(v0, __int_as_float(e0.y)); ACC8(v1, __int_as_float(e1.y));
        ACC8(v2, __int_as_float(e2.y)); ACC8(v3, __int_as_float(e3.y));
    }
    for (; j < r1; j++) {
        int2 e = edges[j];
        float wgt = __int_as_float(e.y);
        uint4 v = *(const uint4*)(t + (size_t)e.x * DH + sl * 8);
        ACC8(v, wgt);
    }

    float4 b0 = *(const float4*)(bias + sl * 8);
    float4 b1v = *(const float4*)(bias + sl * 8 + 4);
    acc[0] = fmaxf(acc[0] + b0.x, 0.f);  acc[1] = fmaxf(acc[1] + b0.y, 0.f);
    acc[2] = fmaxf(acc[2] + b0.z, 0.f);  acc[3] = fmaxf(acc[3] + b0.w, 0.f);
    acc[4] = fmaxf(acc[4] + b1v.x, 0.f); acc[5] = fmaxf(acc[5] + b1v.y, 0.f);
    acc[6] = fmaxf(acc[6] + b1v.z, 0.f); acc[7] = fmaxf(acc[7] + b1v.w, 0.f);

    uint4 o;
    o.x = pk2(acc[0], acc[1]);
    o.y = pk2(acc[2], acc[3]);
    o.z = pk2(acc[4], acc[5]);
    o.w = pk2(acc[6], acc[7]);
    *(uint4*)(outb + (size_t)n * DH + sl * 8) = o;
}

// ---------------- launch ----------------
extern "C" void kernel_launch(void* const* d_in, const int* in_sizes, int n_in,
                              void* d_out, int out_size, void* d_ws, size_t ws_size,
                              hipStream_t stream) {
    const float* x  = (const float*)d_in[0];
    const void*  ei = d_in[1];
    const float* W1 = (const float*)d_in[2];
    const float* b1 = (const float*)d_in[3];
    const float* W2 = (const float*)d_in[4];
    const float* b2 = (const float*)d_in[5];
    const float* Wc = (const float*)d_in[6];
    const float* bc = (const float*)d_in[7];
    float* out = (float*)d_out;

    const int N = in_sizes[0] / DIN;   // 100000
    const int E = in_sizes[1] / 2;     // 800000

    char* ws = (char*)d_ws;
    size_t off = 0;
    auto alloc = [&](size_t bytes) -> void* {
        off = (off + 255) & ~(size_t)255;
        void* p = ws + off;
        off += bytes;
        return p;
    };

    int*   flag      = (int*)alloc(4);
    int*   counts    = (int*)alloc((size_t)N * 4);   // counts + cursor contiguous:
    int*   cursor    = (int*)alloc((size_t)N * 4);   // one memset clears both
    int*   row_ptr   = (int*)alloc((size_t)(N + 1) * 4);
    int2*  edges     = (int2*)alloc((size_t)E * 8);
    int*   blocksums = (int*)alloc(1024 * 4);
    float* dinv      = (float*)alloc((size_t)N * 4);
    unsigned short* Bt1   = (unsigned short*)alloc((size_t)DH * DIN * 2);
    unsigned short* Bt2   = (unsigned short*)alloc((size_t)DH * DH * 2);
    unsigned short* Btc   = (unsigned short*)alloc((size_t)DOUT * DH * 2);
    unsigned short* t_buf = (unsigned short*)alloc((size_t)N * DH * 2);
    unsigned short* a_buf = (unsigned short*)alloc((size_t)N * DH * 2);

    const int NB = (N + SCAN_ELEMS - 1) / SCAN_ELEMS;
    const int gM64  = (N + 63) / 64;
    const int gM128 = (N + 127) / 128;

    // dtype detection + weight prep
    detect_i64<<<1, 256, 0, stream>>>((const unsigned long long*)ei, 1024,
                                      (unsigned long long)N, flag);
    transpose_w<<<(DIN * DH + 255) / 256, 256, 0, stream>>>(W1, Bt1, DIN, DH);
    transpose_w<<<(DH * DH + 255) / 256, 256, 0, stream>>>(W2, Bt2, DH, DH);
    transpose_w<<<(DH * DOUT + 255) / 256, 256, 0, stream>>>(Wc, Btc, DH, DOUT);

    // degrees + CSR (single memset clears counts AND cursor)
    hipMemsetAsync(counts, 0, (size_t)N * 8 + 256, stream);
    count_deg<<<(E + 255) / 256, 256, 0, stream>>>(ei, flag, E, counts);
    compute_dinv<<<(N + 255) / 256, 256, 0, stream>>>(counts, dinv, N);
    scan1<<<NB, SCAN_BLOCK, 0, stream>>>(counts, row_ptr, blocksums, N);
    scan2<<<1, SCAN_BLOCK, 0, stream>>>(blocksums, NB);
    scan3<<<(N + 1 + 255) / 256, 256, 0, stream>>>(row_ptr, blocksums, N, E);
    fill_csr<<<(E + 255) / 256, 256, 0, stream>>>(ei, flag, E, row_ptr, cursor, edges, dinv);

    // layer 1 (round-10 staged GEMM)
    gemm_mfma<true><<<gM64, 256, 0, stream>>>(x, Bt1, t_buf, N, DIN);
    aggregate_bf<<<(N + 7) / 8, 256, 0, stream>>>(t_buf, dinv, row_ptr, edges, b1, a_buf, N);
    // layer 2 (persistent-B)
    gemm2_persist<<<256, 512, 0, stream>>>(a_buf, Bt2, t_buf, N);
    aggregate_bf<<<(N + 7) / 8, 256, 0, stream>>>(t_buf, dinv, row_ptr, edges, b2, a_buf, N);
    // head
    gemm_head<<<gM128, 256, 0, stream>>>(a_buf, Btc, bc, out, N);
}

// Round 13
// 346.864 us; speedup vs baseline: 1.0613x; 1.0203x over previous
//
#include <hip/hip_runtime.h>
#include <cstdint>

#define DIN 512
#define DH  256
#define DOUT 64

typedef __attribute__((ext_vector_type(8))) short bf16x8;
typedef __attribute__((ext_vector_type(4))) float f32x4;
typedef unsigned int uint32;

__device__ __forceinline__ unsigned short f2bf(float f) {
    uint32 u = __float_as_uint(f);
    u += 0x7fff + ((u >> 16) & 1);          // RNE
    return (unsigned short)(u >> 16);
}
__device__ __forceinline__ float bflo(uint32 u) { return __uint_as_float(u << 16); }
__device__ __forceinline__ float bfhi(uint32 u) { return __uint_as_float(u & 0xffff0000u); }
__device__ __forceinline__ uint32 pk2(float lo, float hi) {
    return (uint32)f2bf(lo) | ((uint32)f2bf(hi) << 16);
}

// ---------------- edge_index dtype detection ----------------
__global__ void detect_i64(const unsigned long long* ei, int n_check,
                           unsigned long long bound, int* flag) {
    __shared__ int ok;
    if (threadIdx.x == 0) ok = 1;
    __syncthreads();
    int bad = 0;
    for (int i = threadIdx.x; i < n_check; i += blockDim.x) {
        if (ei[i] >= bound) bad = 1;
    }
    if (bad) ok = 0;
    __syncthreads();
    if (threadIdx.x == 0) *flag = ok;
}

__device__ __forceinline__ int get_idx(const void* ei, int is64, int pos) {
    if (is64) return (int)((const long long*)ei)[pos];
    return ((const int*)ei)[pos];
}

// ---------------- degree count / dinv ----------------
__global__ void count_deg(const void* ei, const int* flag, int E, int* counts) {
    const int is64 = *flag;
    int e = blockIdx.x * blockDim.x + threadIdx.x;
    if (e >= E) return;
    int d = get_idx(ei, is64, E + e);
    atomicAdd(&counts[d], 1);
}

__global__ void compute_dinv(const int* counts, float* dinv, int N) {
    int i = blockIdx.x * blockDim.x + threadIdx.x;
    if (i < N) dinv[i] = rsqrtf((float)counts[i] + 1.0f);
}

// ---------------- exclusive scan ----------------
#define SCAN_BLOCK 256
#define SCAN_ELEMS 1024

__global__ void scan1(const int* counts, int* out, int* blocksums, int N) {
    __shared__ int sh[SCAN_BLOCK];
    int base = blockIdx.x * SCAN_ELEMS;
    int t = threadIdx.x;
    int v[4];
    int s = 0;
    #pragma unroll
    for (int j = 0; j < 4; j++) {
        int idx = base + t * 4 + j;
        v[j] = (idx < N) ? counts[idx] : 0;
        s += v[j];
    }
    sh[t] = s;
    __syncthreads();
    for (int off = 1; off < SCAN_BLOCK; off <<= 1) {
        int x = (t >= off) ? sh[t - off] : 0;
        __syncthreads();
        sh[t] += x;
        __syncthreads();
    }
    int run = (t == 0) ? 0 : sh[t - 1];
    #pragma unroll
    for (int j = 0; j < 4; j++) {
        int idx = base + t * 4 + j;
        if (idx < N) out[idx] = run;
        run += v[j];
    }
    if (t == SCAN_BLOCK - 1) blocksums[blockIdx.x] = sh[t];
}

__global__ void scan2(int* blocksums, int NB) {
    __shared__ int sh[SCAN_BLOCK];
    int t = threadIdx.x;
    sh[t] = (t < NB) ? blocksums[t] : 0;
    __syncthreads();
    for (int off = 1; off < SCAN_BLOCK; off <<= 1) {
        int x = (t >= off) ? sh[t - off] : 0;
        __syncthreads();
        sh[t] += x;
        __syncthreads();
    }
    if (t < NB) blocksums[t] = (t == 0) ? 0 : sh[t - 1];
}

__global__ void scan3(int* row_ptr, const int* blocksums, int N, int E) {
    int i = blockIdx.x * blockDim.x + threadIdx.x;
    if (i < N) row_ptr[i] += blocksums[i / SCAN_ELEMS];
    if (i == N) row_ptr[N] = E;
}

// ---------------- CSR fill (packed edge: col + weight bits) ----------------
__global__ void fill_csr(const void* ei, const int* flag, int E,
                         const int* row_ptr, int* cursor, int2* edges,
                         const float* dinv) {
    const int is64 = *flag;
    int e = blockIdx.x * blockDim.x + threadIdx.x;
    if (e >= E) return;
    int d = get_idx(ei, is64, E + e);
    int s = get_idx(ei, is64, e);
    int pos = row_ptr[d] + atomicAdd(&cursor[d], 1);
    edges[pos] = make_int2(s, __float_as_int(dinv[s] * dinv[d]));
}

// ---------------- weight transpose+convert: W[K][Nw] f32 -> Bt[Nw][K] bf16 ----------------
__global__ void transpose_w(const float* __restrict__ W, unsigned short* __restrict__ Bt,
                            int K, int Nw) {
    int i = blockIdx.x * blockDim.x + threadIdx.x;
    if (i >= K * Nw) return;
    int k = i / Nw, n = i % Nw;
    Bt[(size_t)n * K + k] = f2bf(W[i]);
}

// ---------------- GEMM1 (round-4/10 proven): C[M,256]=A[M,K]*Bt[256,K]^T ----------------
// BM=64 BN=256 BK=64, 256 threads (4 waves). A+B staged, XOR-swizzled LDS, 40 KB.
template <bool A_FP32>
__global__ __launch_bounds__(256) void gemm_mfma(const void* __restrict__ Ap,
                                                 const unsigned short* __restrict__ Bt,
                                                 unsigned short* __restrict__ C,
                                                 int M, int K) {
    __shared__ unsigned short lds[20480];   // As[64][64] | Bs[256][64] = 40 KB
    unsigned short* As = lds;
    unsigned short* Bs = lds + 4096;
    const int tid = threadIdx.x;
    const int w = tid >> 6, l = tid & 63;
    const int m0 = blockIdx.x * 64;

    f32x4 acc[4][4] = {};

    for (int k0 = 0; k0 < K; k0 += 64) {
        // ---- stage B: 256x64 bf16, source granule pre-swizzled ----
        #pragma unroll
        for (int i = 0; i < 8; i++) {
            int row = i * 32 + (tid >> 3);
            int gq = (tid & 7) ^ (row & 7);
            const unsigned short* src = Bt + (size_t)row * K + k0 + gq * 8;
            unsigned short* dst = Bs + row * 64 + (tid & 7) * 8;
            __builtin_amdgcn_global_load_lds(
                (const __attribute__((address_space(1))) uint32*)src,
                (__attribute__((address_space(3))) uint32*)dst, 16, 0, 0);
        }
        // ---- stage A: 64x64 ----
        if (A_FP32) {
            const float* Af = (const float*)Ap;
            #pragma unroll
            for (int i = 0; i < 2; i++) {
                int row = i * 32 + (tid >> 3);
                int g = tid & 7;
                int rg = m0 + row; if (rg > M - 1) rg = M - 1;
                const float* s = Af + (size_t)rg * K + k0 + g * 8;
                float4 v0 = *(const float4*)s;
                float4 v1 = *(const float4*)(s + 4);
                uint4 o;
                o.x = pk2(v0.x, v0.y); o.y = pk2(v0.z, v0.w);
                o.z = pk2(v1.x, v1.y); o.w = pk2(v1.z, v1.w);
                *(uint4*)(As + row * 64 + ((g ^ (row & 7)) * 8)) = o;
            }
        } else {
            const unsigned short* Ab = (const unsigned short*)Ap;
            #pragma unroll
            for (int i = 0; i < 2; i++) {
                int row = i * 32 + (tid >> 3);
                int gq = (tid & 7) ^ (row & 7);
                int rg = m0 + row; if (rg > M - 1) rg = M - 1;
                const unsigned short* src = Ab + (size_t)rg * K + k0 + gq * 8;
                unsigned short* dst = As + row * 64 + (tid & 7) * 8;
                __builtin_amdgcn_global_load_lds(
                    (const __attribute__((address_space(1))) uint32*)src,
                    (__attribute__((address_space(3))) uint32*)dst, 16, 0, 0);
            }
        }
        __syncthreads();
        // ---- compute (swizzled ds_read) ----
        #pragma unroll
        for (int ks = 0; ks < 2; ks++) {
            bf16x8 a[4], b[4];
            #pragma unroll
            for (int m = 0; m < 4; m++) {
                int arow = m * 16 + (l & 15);
                int ag = (ks * 4 + (l >> 4)) ^ (arow & 7);
                a[m] = *(const bf16x8*)(As + arow * 64 + ag * 8);
            }
            #pragma unroll
            for (int n = 0; n < 4; n++) {
                int brow = w * 64 + n * 16 + (l & 15);
                int bg = (ks * 4 + (l >> 4)) ^ (brow & 7);
                b[n] = *(const bf16x8*)(Bs + brow * 64 + bg * 8);
            }
            #pragma unroll
            for (int m = 0; m < 4; m++)
                #pragma unroll
                for (int n = 0; n < 4; n++)
                    acc[m][n] = __builtin_amdgcn_mfma_f32_16x16x32_bf16(a[m], b[n], acc[m][n], 0, 0, 0);
        }
        __syncthreads();
    }

    // ---- epilogue: per-wave 64x64 region -> coalesced 16B stores ----
    unsigned short* ep = lds + w * 4096;
    #pragma unroll
    for (int m = 0; m < 4; m++)
        #pragma unroll
        for (int n = 0; n < 4; n++)
            #pragma unroll
            for (int r = 0; r < 4; r++)
                ep[(m * 16 + (l >> 4) * 4 + r) * 64 + n * 16 + (l & 15)] = f2bf(acc[m][n][r]);
    __syncthreads();
    #pragma unroll
    for (int p = 0; p < 8; p++) {
        int row = p * 8 + (l >> 3);
        int gr = m0 + row;
        uint4 v = *(const uint4*)(ep + row * 64 + (l & 7) * 8);
        if (gr < M)
            *(uint4*)(C + (size_t)gr * 256 + w * 64 + (l & 7) * 8) = v;
    }
}

// ---------------- GEMM2 persistent-B: C[M,256] = A[M,256] @ Bt[256,256]^T ----------------
// 512 threads (8 waves, 2x4). Whole Bt2 (128 KB) LDS-resident, loaded once.
__global__ __launch_bounds__(512) void gemm2_persist(const unsigned short* __restrict__ A,
                                                     const unsigned short* __restrict__ Bt,
                                                     unsigned short* __restrict__ C,
                                                     int M) {
    __shared__ unsigned short lds[73728];   // Bs 128 KB + As 2x8 KB = 144 KB
    unsigned short* Bs = lds;               // [256 rows(n)][256 cols(k)], swizzled granules
    unsigned short* As = lds + 65536;       // 2 bufs of 4096 ushorts ([64][64])
    const int tid = threadIdx.x;
    const int w = tid >> 6, l = tid & 63;
    const int wr = w >> 2, wc = w & 3;      // 2 x 4 wave grid

    // ---- load ALL of Bt once (8192 granules of 16B; 16 per thread) ----
    #pragma unroll
    for (int i = 0; i < 16; i++) {
        int gi = i * 512 + tid;             // 0..8191
        int r = gi >> 5, g = gi & 31;       // row, dest granule (32 granules/row)
        int gs = g ^ (r & 7);               // pre-swizzled source granule
        __builtin_amdgcn_global_load_lds(
            (const __attribute__((address_space(1))) uint32*)(Bt + (size_t)r * 256 + gs * 8),
            (__attribute__((address_space(3))) uint32*)(Bs + (size_t)gi * 8), 16, 0, 0);
    }

    const int sr = tid >> 3;                // A-stage row 0..63
    const int sg = tid & 7;                 // A-stage dest granule

    for (int mt = blockIdx.x; mt * 64 < M; mt += gridDim.x) {
        const int m0 = mt * 64;
        {
            int rg = m0 + sr; if (rg > M - 1) rg = M - 1;
            int gq = sg ^ (sr & 7);
            __builtin_amdgcn_global_load_lds(
                (const __attribute__((address_space(1))) uint32*)(A + (size_t)rg * 256 + gq * 8),
                (__attribute__((address_space(3))) uint32*)(As + tid * 8), 16, 0, 0);
        }
        __syncthreads();

        f32x4 acc[2][4] = {};
        #pragma unroll
        for (int k = 0; k < 4; k++) {
            if (k < 3) {
                int rg = m0 + sr; if (rg > M - 1) rg = M - 1;
                int gq = sg ^ (sr & 7);
                __builtin_amdgcn_global_load_lds(
                    (const __attribute__((address_space(1))) uint32*)(A + (size_t)rg * 256 + (k + 1) * 64 + gq * 8),
                    (__attribute__((address_space(3))) uint32*)(As + ((k + 1) & 1) * 4096 + tid * 8), 16, 0, 0);
            }
            const unsigned short* Ab = As + (k & 1) * 4096;
            #pragma unroll
            for (int ks = 0; ks < 2; ks++) {
                bf16x8 a[2], b[4];
                #pragma unroll
                for (int m = 0; m < 2; m++) {
                    int ar = wr * 32 + m * 16 + (l & 15);
                    int q = (ks * 4 + (l >> 4)) ^ (ar & 7);
                    a[m] = *(const bf16x8*)(Ab + ar * 64 + q * 8);
                }
                #pragma unroll
                for (int n = 0; n < 4; n++) {
                    int br = wc * 64 + n * 16 + (l & 15);
                    int gabs = k * 8 + ks * 4 + (l >> 4);
                    int q = gabs ^ (br & 7);
                    b[n] = *(const bf16x8*)(Bs + br * 256 + q * 8);
                }
                #pragma unroll
                for (int m = 0; m < 2; m++)
                    #pragma unroll
                    for (int n = 0; n < 4; n++)
                        acc[m][n] = __builtin_amdgcn_mfma_f32_16x16x32_bf16(a[m], b[n], acc[m][n], 0, 0, 0);
            }
            __syncthreads();
        }

        #pragma unroll
        for (int m = 0; m < 2; m++)
            #pragma unroll
            for (int r = 0; r < 4; r++) {
                int row = m0 + wr * 32 + m * 16 + (l >> 4) * 4 + r;
                if (row >= M) continue;
                #pragma unroll
                for (int n = 0; n < 4; n++) {
                    int col = wc * 64 + n * 16 + (l & 15);
                    C[(size_t)row * 256 + col] = f2bf(acc[m][n][r]);
                }
            }
    }
}

// ---------------- head GEMM: out[M,64] = A[M,256]*Bt[64,256]^T + bias, f32 out ----------------
__global__ __launch_bounds__(256) void gemm_head(const unsigned short* __restrict__ A,
                                                 const unsigned short* __restrict__ Bt,
                                                 const float* __restrict__ bias,
                                                 float* __restrict__ out, int M) {
    __shared__ unsigned short As[128 * 64];
    __shared__ unsigned short Bs[64 * 64];
    const int tid = threadIdx.x;
    const int w = tid >> 6, l = tid & 63;
    const int m0 = blockIdx.x * 128;
    const int wr = w >> 1, wc = w & 1;
    f32x4 acc[4][2] = {};

    for (int k0 = 0; k0 < 256; k0 += 64) {
        #pragma unroll
        for (int i = 0; i < 4; i++) {
            int row = i * 32 + (tid >> 3);
            int gq = (tid & 7) ^ (row & 7);
            int rg = m0 + row; if (rg > M - 1) rg = M - 1;
            __builtin_amdgcn_global_load_lds(
                (const __attribute__((address_space(1))) uint32*)(A + (size_t)rg * 256 + k0 + gq * 8),
                (__attribute__((address_space(3))) uint32*)(As + row * 64 + (tid & 7) * 8), 16, 0, 0);
        }
        #pragma unroll
        for (int i = 0; i < 2; i++) {
            int row = i * 32 + (tid >> 3);
            int gq = (tid & 7) ^ (row & 7);
            __builtin_amdgcn_global_load_lds(
                (const __attribute__((address_space(1))) uint32*)(Bt + (size_t)row * 256 + k0 + gq * 8),
                (__attribute__((address_space(3))) uint32*)(Bs + row * 64 + (tid & 7) * 8), 16, 0, 0);
        }
        __syncthreads();
        #pragma unroll
        for (int ks = 0; ks < 2; ks++) {
            bf16x8 a[4], b[2];
            #pragma unroll
            for (int m = 0; m < 4; m++) {
                int arow = wr * 64 + m * 16 + (l & 15);
                int ag = (ks * 4 + (l >> 4)) ^ (arow & 7);
                a[m] = *(const bf16x8*)(As + arow * 64 + ag * 8);
            }
            #pragma unroll
            for (int n = 0; n < 2; n++) {
                int brow = wc * 32 + n * 16 + (l & 15);
                int bg = (ks * 4 + (l >> 4)) ^ (brow & 7);
                b[n] = *(const bf16x8*)(Bs + brow * 64 + bg * 8);
            }
            #pragma unroll
            for (int m = 0; m < 4; m++)
                #pragma unroll
                for (int n = 0; n < 2; n++)
                    acc[m][n] = __builtin_amdgcn_mfma_f32_16x16x32_bf16(a[m], b[n], acc[m][n], 0, 0, 0);
        }
        __syncthreads();
    }
    #pragma unroll
    for (int m = 0; m < 4; m++)
        #pragma unroll
        for (int n = 0; n < 2; n++)
            #pragma unroll
            for (int r = 0; r < 4; r++) {
                int gr = m0 + wr * 64 + m * 16 + (l >> 4) * 4 + r;
                int col = wc * 32 + n * 16 + (l & 15);
                if (gr < M) out[(size_t)gr * 64 + col] = acc[m][n][r] + bias[col];
            }
}

// ---------------- aggregation: 2 nodes/wave, 16B lanes, packed edges, 4x unroll ----------------
#define ACC8(v, wgt)                                    \
    do {                                                \
        acc[0] = fmaf(wgt, bflo(v.x), acc[0]);          \
        acc[1] = fmaf(wgt, bfhi(v.x), acc[1]);          \
        acc[2] = fmaf(wgt, bflo(v.y), acc[2]);          \
        acc[3] = fmaf(wgt, bfhi(v.y), acc[3]);          \
        acc[4] = fmaf(wgt, bflo(v.z), acc[4]);          \
        acc[5] = fmaf(wgt, bfhi(v.z), acc[5]);          \
        acc[6] = fmaf(wgt, bflo(v.w), acc[6]);          \
        acc[7] = fmaf(wgt, bfhi(v.w), acc[7]);          \
    } while (0)

__global__ __launch_bounds__(256) void aggregate_bf(const unsigned short* __restrict__ t,
                                                    const float* __restrict__ dinv,
                                                    const int* __restrict__ row_ptr,
                                                    const int2* __restrict__ edges,
                                                    const float* __restrict__ bias,
                                                    unsigned short* __restrict__ outb,
                                                    int N) {
    int wave = threadIdx.x >> 6;
    int lane = threadIdx.x & 63;
    int half = lane >> 5;          // which node of the pair
    int sl = lane & 31;            // owns feats [sl*8, sl*8+8)
    int n = blockIdx.x * 8 + wave * 2 + half;
    if (n >= N) return;

    float dn = dinv[n];
    int r0 = row_ptr[n], r1 = row_ptr[n + 1];

    float acc[8];
    {
        uint4 sv = *(const uint4*)(t + (size_t)n * DH + sl * 8);
        float sn = dn * dn;
        acc[0] = bflo(sv.x) * sn; acc[1] = bfhi(sv.x) * sn;
        acc[2] = bflo(sv.y) * sn; acc[3] = bfhi(sv.y) * sn;
        acc[4] = bflo(sv.z) * sn; acc[5] = bfhi(sv.z) * sn;
        acc[6] = bflo(sv.w) * sn; acc[7] = bfhi(sv.w) * sn;
    }

    int j = r0;
    for (; j + 4 <= r1; j += 4) {
        int2 e0 = edges[j + 0], e1 = edges[j + 1];
        int2 e2 = edges[j + 2], e3 = edges[j + 3];
        uint4 v0 = *(const uint4*)(t + (size_t)e0.x * DH + sl * 8);
        uint4 v1 = *(const uint4*)(t + (size_t)e1.x * DH + sl * 8);
        uint4 v2 = *(const uint4*)(t + (size_t)e2.x * DH + sl * 8);
        uint4 v3 = *(const uint4*)(t + (size_t)e3.x * DH + sl * 8);
        float w0 = __int_as_float(e0.y), w1 = __int_as_float(e1.y);
        float w2 = __int_as_float(e2.y), w3 = __int_as_float(e3.y);
        ACC8(v0, w0); ACC8(v1, w1); ACC8(v2, w2); ACC8(v3, w3);
    }
    for (; j < r1; j++) {
        int2 e = edges[j];
        float wgt = __int_as_float(e.y);
        uint4 v = *(const uint4*)(t + (size_t)e.x * DH + sl * 8);
        ACC8(v, wgt);
    }

    float4 b0 = *(const float4*)(bias + sl * 8);
    float4 b1v = *(const float4*)(bias + sl * 8 + 4);
    acc[0] = fmaxf(acc[0] + b0.x, 0.f);  acc[1] = fmaxf(acc[1] + b0.y, 0.f);
    acc[2] = fmaxf(acc[2] + b0.z, 0.f);  acc[3] = fmaxf(acc[3] + b0.w, 0.f);
    acc[4] = fmaxf(acc[4] + b1v.x, 0.f); acc[5] = fmaxf(acc[5] + b1v.y, 0.f);
    acc[6] = fmaxf(acc[6] + b1v.z, 0.f); acc[7] = fmaxf(acc[7] + b1v.w, 0.f);

    uint4 o;
    o.x = pk2(acc[0], acc[1]);
    o.y = pk2(acc[2], acc[3]);
    o.z = pk2(acc[4], acc[5]);
    o.w = pk2(acc[6], acc[7]);
    *(uint4*)(outb + (size_t)n * DH + sl * 8) = o;
}

// ---------------- launch ----------------
extern "C" void kernel_launch(void* const* d_in, const int* in_sizes, int n_in,
                              void* d_out, int out_size, void* d_ws, size_t ws_size,
                              hipStream_t stream) {
    const float* x  = (const float*)d_in[0];
    const void*  ei = d_in[1];
    const float* W1 = (const float*)d_in[2];
    const float* b1 = (const float*)d_in[3];
    const float* W2 = (const float*)d_in[4];
    const float* b2 = (const float*)d_in[5];
    const float* Wc = (const float*)d_in[6];
    const float* bc = (const float*)d_in[7];
    float* out = (float*)d_out;

    const int N = in_sizes[0] / DIN;   // 100000
    const int E = in_sizes[1] / 2;     // 800000

    char* ws = (char*)d_ws;
    size_t off = 0;
    auto alloc = [&](size_t bytes) -> void* {
        off = (off + 255) & ~(size_t)255;
        void* p = ws + off;
        off += bytes;
        return p;
    };

    int*   flag      = (int*)alloc(4);
    int*   counts    = (int*)alloc((size_t)N * 4);   // counts + cursor contiguous:
    int*   cursor    = (int*)alloc((size_t)N * 4);   // one memset clears both
    int*   row_ptr   = (int*)alloc((size_t)(N + 1) * 4);
    int2*  edges     = (int2*)alloc((size_t)E * 8);
    int*   blocksums = (int*)alloc(1024 * 4);
    float* dinv      = (float*)alloc((size_t)N * 4);
    unsigned short* Bt1   = (unsigned short*)alloc((size_t)DH * DIN * 2);
    unsigned short* Bt2   = (unsigned short*)alloc((size_t)DH * DH * 2);
    unsigned short* Btc   = (unsigned short*)alloc((size_t)DOUT * DH * 2);
    unsigned short* t_buf = (unsigned short*)alloc((size_t)N * DH * 2);
    unsigned short* a_buf = (unsigned short*)alloc((size_t)N * DH * 2);

    const int NB = (N + SCAN_ELEMS - 1) / SCAN_ELEMS;
    const int gM64  = (N + 63) / 64;
    const int gM128 = (N + 127) / 128;

    // dtype detection + weight prep
    detect_i64<<<1, 256, 0, stream>>>((const unsigned long long*)ei, 1024,
                                      (unsigned long long)N, flag);
    transpose_w<<<(DIN * DH + 255) / 256, 256, 0, stream>>>(W1, Bt1, DIN, DH);
    transpose_w<<<(DH * DH + 255) / 256, 256, 0, stream>>>(W2, Bt2, DH, DH);
    transpose_w<<<(DH * DOUT + 255) / 256, 256, 0, stream>>>(Wc, Btc, DH, DOUT);

    // degrees + CSR (single memset clears counts AND cursor)
    hipMemsetAsync(counts, 0, (size_t)N * 8 + 256, stream);
    count_deg<<<(E + 255) / 256, 256, 0, stream>>>(ei, flag, E, counts);
    compute_dinv<<<(N + 255) / 256, 256, 0, stream>>>(counts, dinv, N);
    scan1<<<NB, SCAN_BLOCK, 0, stream>>>(counts, row_ptr, blocksums, N);
    scan2<<<1, SCAN_BLOCK, 0, stream>>>(blocksums, NB);
    scan3<<<(N + 1 + 255) / 256, 256, 0, stream>>>(row_ptr, blocksums, N, E);
    fill_csr<<<(E + 255) / 256, 256, 0, stream>>>(ei, flag, E, row_ptr, cursor, edges, dinv);

    // layer 1 (round-10 staged GEMM)
    gemm_mfma<true><<<gM64, 256, 0, stream>>>(x, Bt1, t_buf, N, DIN);
    aggregate_bf<<<(N + 7) / 8, 256, 0, stream>>>(t_buf, dinv, row_ptr, edges, b1, a_buf, N);
    // layer 2 (persistent-B)
    gemm2_persist<<<256, 512, 0, stream>>>(a_buf, Bt2, t_buf, N);
    aggregate_bf<<<(N + 7) / 8, 256, 0, stream>>>(t_buf, dinv, row_ptr, edges, b2, a_buf, N);
    // head
    gemm_head<<<gM128, 256, 0, stream>>>(a_buf, Btc, bc, out, N);
}

// Round 14
// 341.418 us; speedup vs baseline: 1.0783x; 1.0159x over previous
//
#include <hip/hip_runtime.h>
#include <cstdint>

#define DIN 512
#define DH  256
#define DOUT 64

typedef __attribute__((ext_vector_type(8))) short bf16x8;
typedef __attribute__((ext_vector_type(4))) float f32x4;
typedef unsigned int uint32;

__device__ __forceinline__ unsigned short f2bf(float f) {
    uint32 u = __float_as_uint(f);
    u += 0x7fff + ((u >> 16) & 1);          // RNE
    return (unsigned short)(u >> 16);
}
__device__ __forceinline__ float bflo(uint32 u) { return __uint_as_float(u << 16); }
__device__ __forceinline__ float bfhi(uint32 u) { return __uint_as_float(u & 0xffff0000u); }
__device__ __forceinline__ uint32 pk2(float lo, float hi) {
    return (uint32)f2bf(lo) | ((uint32)f2bf(hi) << 16);
}

// ---------------- edge_index dtype detection ----------------
__global__ void detect_i64(const unsigned long long* ei, int n_check,
                           unsigned long long bound, int* flag) {
    __shared__ int ok;
    if (threadIdx.x == 0) ok = 1;
    __syncthreads();
    int bad = 0;
    for (int i = threadIdx.x; i < n_check; i += blockDim.x) {
        if (ei[i] >= bound) bad = 1;
    }
    if (bad) ok = 0;
    __syncthreads();
    if (threadIdx.x == 0) *flag = ok;
}

__device__ __forceinline__ int get_idx(const void* ei, int is64, int pos) {
    if (is64) return (int)((const long long*)ei)[pos];
    return ((const int*)ei)[pos];
}

// ---------------- degree count ----------------
__global__ void count_deg(const void* ei, const int* flag, int E, int* counts) {
    const int is64 = *flag;
    int e = blockIdx.x * blockDim.x + threadIdx.x;
    if (e >= E) return;
    int d = get_idx(ei, is64, E + e);
    atomicAdd(&counts[d], 1);
}

// ---------------- exclusive scan (+ fused dinv) ----------------
#define SCAN_BLOCK 256
#define SCAN_ELEMS 1024

__global__ void scan1(const int* counts, int* out, int* blocksums, float* dinv, int N) {
    __shared__ int sh[SCAN_BLOCK];
    int base = blockIdx.x * SCAN_ELEMS;
    int t = threadIdx.x;
    int v[4];
    int s = 0;
    #pragma unroll
    for (int j = 0; j < 4; j++) {
        int idx = base + t * 4 + j;
        v[j] = (idx < N) ? counts[idx] : 0;
        if (idx < N) dinv[idx] = rsqrtf((float)v[j] + 1.0f);   // fused compute_dinv
        s += v[j];
    }
    sh[t] = s;
    __syncthreads();
    for (int off = 1; off < SCAN_BLOCK; off <<= 1) {
        int x = (t >= off) ? sh[t - off] : 0;
        __syncthreads();
        sh[t] += x;
        __syncthreads();
    }
    int run = (t == 0) ? 0 : sh[t - 1];
    #pragma unroll
    for (int j = 0; j < 4; j++) {
        int idx = base + t * 4 + j;
        if (idx < N) out[idx] = run;
        run += v[j];
    }
    if (t == SCAN_BLOCK - 1) blocksums[blockIdx.x] = sh[t];
}

__global__ void scan2(int* blocksums, int NB) {
    __shared__ int sh[SCAN_BLOCK];
    int t = threadIdx.x;
    sh[t] = (t < NB) ? blocksums[t] : 0;
    __syncthreads();
    for (int off = 1; off < SCAN_BLOCK; off <<= 1) {
        int x = (t >= off) ? sh[t - off] : 0;
        __syncthreads();
        sh[t] += x;
        __syncthreads();
    }
    if (t < NB) blocksums[t] = (t == 0) ? 0 : sh[t - 1];
}

__global__ void scan3(int* row_ptr, const int* blocksums, int N, int E) {
    int i = blockIdx.x * blockDim.x + threadIdx.x;
    if (i < N) row_ptr[i] += blocksums[i / SCAN_ELEMS];
    if (i == N) row_ptr[N] = E;
}

// ---------------- CSR fill (packed edge: col + weight bits) ----------------
__global__ void fill_csr(const void* ei, const int* flag, int E,
                         const int* row_ptr, int* cursor, int2* edges,
                         const float* dinv) {
    const int is64 = *flag;
    int e = blockIdx.x * blockDim.x + threadIdx.x;
    if (e >= E) return;
    int d = get_idx(ei, is64, E + e);
    int s = get_idx(ei, is64, e);
    int pos = row_ptr[d] + atomicAdd(&cursor[d], 1);
    edges[pos] = make_int2(s, __float_as_int(dinv[s] * dinv[d]));
}

// ---------------- fused weight prep: all three transposes in one dispatch ----------------
__global__ void prep_weights(const float* __restrict__ W1, const float* __restrict__ W2,
                             const float* __restrict__ Wc,
                             unsigned short* __restrict__ Bt1,
                             unsigned short* __restrict__ Bt2,
                             unsigned short* __restrict__ Btc) {
    const int n1 = DIN * DH;            // 131072
    const int n2 = n1 + DH * DH;        // 196608
    const int n3 = n2 + DH * DOUT;      // 212992
    int i = blockIdx.x * blockDim.x + threadIdx.x;
    if (i < n1) {
        int k = i / DH, n = i % DH;
        Bt1[(size_t)n * DIN + k] = f2bf(W1[i]);
    } else if (i < n2) {
        int j = i - n1;
        int k = j / DH, n = j % DH;
        Bt2[(size_t)n * DH + k] = f2bf(W2[j]);
    } else if (i < n3) {
        int j = i - n2;
        int k = j / DOUT, n = j % DOUT;
        Btc[(size_t)n * DH + k] = f2bf(Wc[j]);
    }
}

// ---------------- GEMM1 (round-4/10 proven): C[M,256]=A[M,K]*Bt[256,K]^T ----------------
// BM=64 BN=256 BK=64, 256 threads (4 waves). A+B staged, XOR-swizzled LDS, 40 KB.
template <bool A_FP32>
__global__ __launch_bounds__(256) void gemm_mfma(const void* __restrict__ Ap,
                                                 const unsigned short* __restrict__ Bt,
                                                 unsigned short* __restrict__ C,
                                                 int M, int K) {
    __shared__ unsigned short lds[20480];   // As[64][64] | Bs[256][64] = 40 KB
    unsigned short* As = lds;
    unsigned short* Bs = lds + 4096;
    const int tid = threadIdx.x;
    const int w = tid >> 6, l = tid & 63;
    const int m0 = blockIdx.x * 64;

    f32x4 acc[4][4] = {};

    for (int k0 = 0; k0 < K; k0 += 64) {
        // ---- stage B: 256x64 bf16, source granule pre-swizzled ----
        #pragma unroll
        for (int i = 0; i < 8; i++) {
            int row = i * 32 + (tid >> 3);
            int gq = (tid & 7) ^ (row & 7);
            const unsigned short* src = Bt + (size_t)row * K + k0 + gq * 8;
            unsigned short* dst = Bs + row * 64 + (tid & 7) * 8;
            __builtin_amdgcn_global_load_lds(
                (const __attribute__((address_space(1))) uint32*)src,
                (__attribute__((address_space(3))) uint32*)dst, 16, 0, 0);
        }
        // ---- stage A: 64x64 ----
        if (A_FP32) {
            const float* Af = (const float*)Ap;
            #pragma unroll
            for (int i = 0; i < 2; i++) {
                int row = i * 32 + (tid >> 3);
                int g = tid & 7;
                int rg = m0 + row; if (rg > M - 1) rg = M - 1;
                const float* s = Af + (size_t)rg * K + k0 + g * 8;
                float4 v0 = *(const float4*)s;
                float4 v1 = *(const float4*)(s + 4);
                uint4 o;
                o.x = pk2(v0.x, v0.y); o.y = pk2(v0.z, v0.w);
                o.z = pk2(v1.x, v1.y); o.w = pk2(v1.z, v1.w);
                *(uint4*)(As + row * 64 + ((g ^ (row & 7)) * 8)) = o;
            }
        } else {
            const unsigned short* Ab = (const unsigned short*)Ap;
            #pragma unroll
            for (int i = 0; i < 2; i++) {
                int row = i * 32 + (tid >> 3);
                int gq = (tid & 7) ^ (row & 7);
                int rg = m0 + row; if (rg > M - 1) rg = M - 1;
                const unsigned short* src = Ab + (size_t)rg * K + k0 + gq * 8;
                unsigned short* dst = As + row * 64 + (tid & 7) * 8;
                __builtin_amdgcn_global_load_lds(
                    (const __attribute__((address_space(1))) uint32*)src,
                    (__attribute__((address_space(3))) uint32*)dst, 16, 0, 0);
            }
        }
        __syncthreads();
        // ---- compute (swizzled ds_read) ----
        #pragma unroll
        for (int ks = 0; ks < 2; ks++) {
            bf16x8 a[4], b[4];
            #pragma unroll
            for (int m = 0; m < 4; m++) {
                int arow = m * 16 + (l & 15);
                int ag = (ks * 4 + (l >> 4)) ^ (arow & 7);
                a[m] = *(const bf16x8*)(As + arow * 64 + ag * 8);
            }
            #pragma unroll
            for (int n = 0; n < 4; n++) {
                int brow = w * 64 + n * 16 + (l & 15);
                int bg = (ks * 4 + (l >> 4)) ^ (brow & 7);
                b[n] = *(const bf16x8*)(Bs + brow * 64 + bg * 8);
            }
            #pragma unroll
            for (int m = 0; m < 4; m++)
                #pragma unroll
                for (int n = 0; n < 4; n++)
                    acc[m][n] = __builtin_amdgcn_mfma_f32_16x16x32_bf16(a[m], b[n], acc[m][n], 0, 0, 0);
        }
        __syncthreads();
    }

    // ---- epilogue: per-wave 64x64 region -> coalesced 16B stores ----
    unsigned short* ep = lds + w * 4096;
    #pragma unroll
    for (int m = 0; m < 4; m++)
        #pragma unroll
        for (int n = 0; n < 4; n++)
            #pragma unroll
            for (int r = 0; r < 4; r++)
                ep[(m * 16 + (l >> 4) * 4 + r) * 64 + n * 16 + (l & 15)] = f2bf(acc[m][n][r]);
    __syncthreads();
    #pragma unroll
    for (int p = 0; p < 8; p++) {
        int row = p * 8 + (l >> 3);
        int gr = m0 + row;
        uint4 v = *(const uint4*)(ep + row * 64 + (l & 7) * 8);
        if (gr < M)
            *(uint4*)(C + (size_t)gr * 256 + w * 64 + (l & 7) * 8) = v;
    }
}

// ---------------- GEMM2 persistent-B: C[M,256] = A[M,256] @ Bt[256,256]^T ----------------
// 512 threads (8 waves, 2x4). Whole Bt2 (128 KB) LDS-resident, loaded once.
__global__ __launch_bounds__(512) void gemm2_persist(const unsigned short* __restrict__ A,
                                                     const unsigned short* __restrict__ Bt,
                                                     unsigned short* __restrict__ C,
                                                     int M) {
    __shared__ unsigned short lds[73728];   // Bs 128 KB + As 2x8 KB = 144 KB
    unsigned short* Bs = lds;               // [256 rows(n)][256 cols(k)], swizzled granules
    unsigned short* As = lds + 65536;       // 2 bufs of 4096 ushorts ([64][64])
    const int tid = threadIdx.x;
    const int w = tid >> 6, l = tid & 63;
    const int wr = w >> 2, wc = w & 3;      // 2 x 4 wave grid

    // ---- load ALL of Bt once (8192 granules of 16B; 16 per thread) ----
    #pragma unroll
    for (int i = 0; i < 16; i++) {
        int gi = i * 512 + tid;             // 0..8191
        int r = gi >> 5, g = gi & 31;       // row, dest granule (32 granules/row)
        int gs = g ^ (r & 7);               // pre-swizzled source granule
        __builtin_amdgcn_global_load_lds(
            (const __attribute__((address_space(1))) uint32*)(Bt + (size_t)r * 256 + gs * 8),
            (__attribute__((address_space(3))) uint32*)(Bs + (size_t)gi * 8), 16, 0, 0);
    }

    const int sr = tid >> 3;                // A-stage row 0..63
    const int sg = tid & 7;                 // A-stage dest granule

    for (int mt = blockIdx.x; mt * 64 < M; mt += gridDim.x) {
        const int m0 = mt * 64;
        {
            int rg = m0 + sr; if (rg > M - 1) rg = M - 1;
            int gq = sg ^ (sr & 7);
            __builtin_amdgcn_global_load_lds(
                (const __attribute__((address_space(1))) uint32*)(A + (size_t)rg * 256 + gq * 8),
                (__attribute__((address_space(3))) uint32*)(As + tid * 8), 16, 0, 0);
        }
        __syncthreads();

        f32x4 acc[2][4] = {};
        #pragma unroll
        for (int k = 0; k < 4; k++) {
            if (k < 3) {
                int rg = m0 + sr; if (rg > M - 1) rg = M - 1;
                int gq = sg ^ (sr & 7);
                __builtin_amdgcn_global_load_lds(
                    (const __attribute__((address_space(1))) uint32*)(A + (size_t)rg * 256 + (k + 1) * 64 + gq * 8),
                    (__attribute__((address_space(3))) uint32*)(As + ((k + 1) & 1) * 4096 + tid * 8), 16, 0, 0);
            }
            const unsigned short* Ab = As + (k & 1) * 4096;
            #pragma unroll
            for (int ks = 0; ks < 2; ks++) {
                bf16x8 a[2], b[4];
                #pragma unroll
                for (int m = 0; m < 2; m++) {
                    int ar = wr * 32 + m * 16 + (l & 15);
                    int q = (ks * 4 + (l >> 4)) ^ (ar & 7);
                    a[m] = *(const bf16x8*)(Ab + ar * 64 + q * 8);
                }
                #pragma unroll
                for (int n = 0; n < 4; n++) {
                    int br = wc * 64 + n * 16 + (l & 15);
                    int gabs = k * 8 + ks * 4 + (l >> 4);
                    int q = gabs ^ (br & 7);
                    b[n] = *(const bf16x8*)(Bs + br * 256 + q * 8);
                }
                #pragma unroll
                for (int m = 0; m < 2; m++)
                    #pragma unroll
                    for (int n = 0; n < 4; n++)
                        acc[m][n] = __builtin_amdgcn_mfma_f32_16x16x32_bf16(a[m], b[n], acc[m][n], 0, 0, 0);
            }
            __syncthreads();
        }

        #pragma unroll
        for (int m = 0; m < 2; m++)
            #pragma unroll
            for (int r = 0; r < 4; r++) {
                int row = m0 + wr * 32 + m * 16 + (l >> 4) * 4 + r;
                if (row >= M) continue;
                #pragma unroll
                for (int n = 0; n < 4; n++) {
                    int col = wc * 64 + n * 16 + (l & 15);
                    C[(size_t)row * 256 + col] = f2bf(acc[m][n][r]);
                }
            }
    }
}

// ---------------- head GEMM: out[M,64] = A[M,256]*Bt[64,256]^T + bias, f32 out ----------------
__global__ __launch_bounds__(256) void gemm_head(const unsigned short* __restrict__ A,
                                                 const unsigned short* __restrict__ Bt,
                                                 const float* __restrict__ bias,
                                                 float* __restrict__ out, int M) {
    __shared__ unsigned short As[128 * 64];
    __shared__ unsigned short Bs[64 * 64];
    const int tid = threadIdx.x;
    const int w = tid >> 6, l = tid & 63;
    const int m0 = blockIdx.x * 128;
    const int wr = w >> 1, wc = w & 1;
    f32x4 acc[4][2] = {};

    for (int k0 = 0; k0 < 256; k0 += 64) {
        #pragma unroll
        for (int i = 0; i < 4; i++) {
            int row = i * 32 + (tid >> 3);
            int gq = (tid & 7) ^ (row & 7);
            int rg = m0 + row; if (rg > M - 1) rg = M - 1;
            __builtin_amdgcn_global_load_lds(
                (const __attribute__((address_space(1))) uint32*)(A + (size_t)rg * 256 + k0 + gq * 8),
                (__attribute__((address_space(3))) uint32*)(As + row * 64 + (tid & 7) * 8), 16, 0, 0);
        }
        #pragma unroll
        for (int i = 0; i < 2; i++) {
            int row = i * 32 + (tid >> 3);
            int gq = (tid & 7) ^ (row & 7);
            __builtin_amdgcn_global_load_lds(
                (const __attribute__((address_space(1))) uint32*)(Bt + (size_t)row * 256 + k0 + gq * 8),
                (__attribute__((address_space(3))) uint32*)(Bs + row * 64 + (tid & 7) * 8), 16, 0, 0);
        }
        __syncthreads();
        #pragma unroll
        for (int ks = 0; ks < 2; ks++) {
            bf16x8 a[4], b[2];
            #pragma unroll
            for (int m = 0; m < 4; m++) {
                int arow = wr * 64 + m * 16 + (l & 15);
                int ag = (ks * 4 + (l >> 4)) ^ (arow & 7);
                a[m] = *(const bf16x8*)(As + arow * 64 + ag * 8);
            }
            #pragma unroll
            for (int n = 0; n < 2; n++) {
                int brow = wc * 32 + n * 16 + (l & 15);
                int bg = (ks * 4 + (l >> 4)) ^ (brow & 7);
                b[n] = *(const bf16x8*)(Bs + brow * 64 + bg * 8);
            }
            #pragma unroll
            for (int m = 0; m < 4; m++)
                #pragma unroll
                for (int n = 0; n < 2; n++)
                    acc[m][n] = __builtin_amdgcn_mfma_f32_16x16x32_bf16(a[m], b[n], acc[m][n], 0, 0, 0);
        }
        __syncthreads();
    }
    #pragma unroll
    for (int m = 0; m < 4; m++)
        #pragma unroll
        for (int n = 0; n < 2; n++)
            #pragma unroll
            for (int r = 0; r < 4; r++) {
                int gr = m0 + wr * 64 + m * 16 + (l >> 4) * 4 + r;
                int col = wc * 32 + n * 16 + (l & 15);
                if (gr < M) out[(size_t)gr * 64 + col] = acc[m][n][r] + bias[col];
            }
}

// ---------------- aggregation: 2 nodes/wave, 16B lanes, packed edges, 4x unroll ----------------
#define ACC8(v, wgt)                                    \
    do {                                                \
        acc[0] = fmaf(wgt, bflo(v.x), acc[0]);          \
        acc[1] = fmaf(wgt, bfhi(v.x), acc[1]);          \
        acc[2] = fmaf(wgt, bflo(v.y), acc[2]);          \
        acc[3] = fmaf(wgt, bfhi(v.y), acc[3]);          \
        acc[4] = fmaf(wgt, bflo(v.z), acc[4]);          \
        acc[5] = fmaf(wgt, bfhi(v.z), acc[5]);          \
        acc[6] = fmaf(wgt, bflo(v.w), acc[6]);          \
        acc[7] = fmaf(wgt, bfhi(v.w), acc[7]);          \
    } while (0)

__global__ __launch_bounds__(256) void aggregate_bf(const unsigned short* __restrict__ t,
                                                    const float* __restrict__ dinv,
                                                    const int* __restrict__ row_ptr,
                                                    const int2* __restrict__ edges,
                                                    const float* __restrict__ bias,
                                                    unsigned short* __restrict__ outb,
                                                    int N) {
    int wave = threadIdx.x >> 6;
    int lane = threadIdx.x & 63;
    int half = lane >> 5;          // which node of the pair
    int sl = lane & 31;            // owns feats [sl*8, sl*8+8)
    int n = blockIdx.x * 8 + wave * 2 + half;
    if (n >= N) return;

    float dn = dinv[n];
    int r0 = row_ptr[n], r1 = row_ptr[n + 1];

    float acc[8];
    {
        uint4 sv = *(const uint4*)(t + (size_t)n * DH + sl * 8);
        float sn = dn * dn;
        acc[0] = bflo(sv.x) * sn; acc[1] = bfhi(sv.x) * sn;
        acc[2] = bflo(sv.y) * sn; acc[3] = bfhi(sv.y) * sn;
        acc[4] = bflo(sv.z) * sn; acc[5] = bfhi(sv.z) * sn;
        acc[6] = bflo(sv.w) * sn; acc[7] = bfhi(sv.w) * sn;
    }

    int j = r0;
    for (; j + 4 <= r1; j += 4) {
        int2 e0 = edges[j + 0], e1 = edges[j + 1];
        int2 e2 = edges[j + 2], e3 = edges[j + 3];
        uint4 v0 = *(const uint4*)(t + (size_t)e0.x * DH + sl * 8);
        uint4 v1 = *(const uint4*)(t + (size_t)e1.x * DH + sl * 8);
        uint4 v2 = *(const uint4*)(t + (size_t)e2.x * DH + sl * 8);
        uint4 v3 = *(const uint4*)(t + (size_t)e3.x * DH + sl * 8);
        float w0 = __int_as_float(e0.y), w1 = __int_as_float(e1.y);
        float w2 = __int_as_float(e2.y), w3 = __int_as_float(e3.y);
        ACC8(v0, w0); ACC8(v1, w1); ACC8(v2, w2); ACC8(v3, w3);
    }
    for (; j < r1; j++) {
        int2 e = edges[j];
        float wgt = __int_as_float(e.y);
        uint4 v = *(const uint4*)(t + (size_t)e.x * DH + sl * 8);
        ACC8(v, wgt);
    }

    float4 b0 = *(const float4*)(bias + sl * 8);
    float4 b1v = *(const float4*)(bias + sl * 8 + 4);
    acc[0] = fmaxf(acc[0] + b0.x, 0.f);  acc[1] = fmaxf(acc[1] + b0.y, 0.f);
    acc[2] = fmaxf(acc[2] + b0.z, 0.f);  acc[3] = fmaxf(acc[3] + b0.w, 0.f);
    acc[4] = fmaxf(acc[4] + b1v.x, 0.f); acc[5] = fmaxf(acc[5] + b1v.y, 0.f);
    acc[6] = fmaxf(acc[6] + b1v.z, 0.f); acc[7] = fmaxf(acc[7] + b1v.w, 0.f);

    uint4 o;
    o.x = pk2(acc[0], acc[1]);
    o.y = pk2(acc[2], acc[3]);
    o.z = pk2(acc[4], acc[5]);
    o.w = pk2(acc[6], acc[7]);
    *(uint4*)(outb + (size_t)n * DH + sl * 8) = o;
}

// ---------------- launch ----------------
extern "C" void kernel_launch(void* const* d_in, const int* in_sizes, int n_in,
                              void* d_out, int out_size, void* d_ws, size_t ws_size,
                              hipStream_t stream) {
    const float* x  = (const float*)d_in[0];
    const void*  ei = d_in[1];
    const float* W1 = (const float*)d_in[2];
    const float* b1 = (const float*)d_in[3];
    const float* W2 = (const float*)d_in[4];
    const float* b2 = (const float*)d_in[5];
    const float* Wc = (const float*)d_in[6];
    const float* bc = (const float*)d_in[7];
    float* out = (float*)d_out;

    const int N = in_sizes[0] / DIN;   // 100000
    const int E = in_sizes[1] / 2;     // 800000

    char* ws = (char*)d_ws;
    size_t off = 0;
    auto alloc = [&](size_t bytes) -> void* {
        off = (off + 255) & ~(size_t)255;
        void* p = ws + off;
        off += bytes;
        return p;
    };

    int*   flag      = (int*)alloc(4);
    int*   counts    = (int*)alloc((size_t)N * 4);   // counts + cursor contiguous:
    int*   cursor    = (int*)alloc((size_t)N * 4);   // one memset clears both
    int*   row_ptr   = (int*)alloc((size_t)(N + 1) * 4);
    int2*  edges     = (int2*)alloc((size_t)E * 8);
    int*   blocksums = (int*)alloc(1024 * 4);
    float* dinv      = (float*)alloc((size_t)N * 4);
    unsigned short* Bt1   = (unsigned short*)alloc((size_t)DH * DIN * 2);
    unsigned short* Bt2   = (unsigned short*)alloc((size_t)DH * DH * 2);
    unsigned short* Btc   = (unsigned short*)alloc((size_t)DOUT * DH * 2);
    unsigned short* t_buf = (unsigned short*)alloc((size_t)N * DH * 2);
    unsigned short* a_buf = (unsigned short*)alloc((size_t)N * DH * 2);

    const int NB = (N + SCAN_ELEMS - 1) / SCAN_ELEMS;
    const int gM64  = (N + 63) / 64;
    const int gM128 = (N + 127) / 128;
    const int NW = DIN * DH + DH * DH + DH * DOUT;   // 212992 weight elements

    // dtype detection + fused weight prep
    detect_i64<<<1, 256, 0, stream>>>((const unsigned long long*)ei, 1024,
                                      (unsigned long long)N, flag);
    prep_weights<<<(NW + 255) / 256, 256, 0, stream>>>(W1, W2, Wc, Bt1, Bt2, Btc);

    // degrees + CSR (single memset clears counts AND cursor; dinv fused into scan1)
    hipMemsetAsync(counts, 0, (size_t)N * 8 + 256, stream);
    count_deg<<<(E + 255) / 256, 256, 0, stream>>>(ei, flag, E, counts);
    scan1<<<NB, SCAN_BLOCK, 0, stream>>>(counts, row_ptr, blocksums, dinv, N);
    scan2<<<1, SCAN_BLOCK, 0, stream>>>(blocksums, NB);
    scan3<<<(N + 1 + 255) / 256, 256, 0, stream>>>(row_ptr, blocksums, N, E);
    fill_csr<<<(E + 255) / 256, 256, 0, stream>>>(ei, flag, E, row_ptr, cursor, edges, dinv);

    // layer 1 (round-10 staged GEMM)
    gemm_mfma<true><<<gM64, 256, 0, stream>>>(x, Bt1, t_buf, N, DIN);
    aggregate_bf<<<(N + 7) / 8, 256, 0, stream>>>(t_buf, dinv, row_ptr, edges, b1, a_buf, N);
    // layer 2 (persistent-B)
    gemm2_persist<<<256, 512, 0, stream>>>(a_buf, Bt2, t_buf, N);
    aggregate_bf<<<(N + 7) / 8, 256, 0, stream>>>(t_buf, dinv, row_ptr, edges, b2, a_buf, N);
    // head
    gemm_head<<<gM128, 256, 0, stream>>>(a_buf, Btc, bc, out, N);
}